// Round 19
// baseline (1270.679 us; speedup 1.0000x reference)
//
#include <hip/hip_runtime.h>
#include <math.h>

#define HH 256
#define WW 256
#define CC 64
#define PLANE (HH*WW)

typedef short s16x8 __attribute__((ext_vector_type(8)));
typedef float f32x16 __attribute__((ext_vector_type(16)));
typedef unsigned int uint;
typedef uint u32x4v __attribute__((ext_vector_type(4)));

__device__ inline uint bf16rne(float f) {
    uint u = __float_as_uint(f);
    return (u + 0x7FFFu + ((u >> 16) & 1u)) >> 16;
}
__device__ inline float bf16val(uint h) { return __uint_as_float(h << 16); }
__device__ inline s16x8 fragpack(uint4 q) {
    u32x4v t = {q.x, q.y, q.z, q.w};
    return __builtin_bit_cast(s16x8, t);
}
// activation fragment-slot layout: dword (pix, dwi) at
//   (pix>>5)*1024 + (dwi>>2)*128 + (pix&31)*4 + (dwi&3)
__device__ inline size_t chunk_addr(int pix, int c2) {
    return (size_t)(pix >> 5) * 1024 + c2 * 128 + (pix & 31) * 4;
}
// weight fragment-slot layout: dword (tap, oc, dwi) at
//   tap*2048 + (dwi>>2)*256 + oc*4 + (dwi&3)   -> lane-dense dwordx4 loads

// ---------------- weight prep: split fp32 W into bf16 hi/lo ----------------
__global__ __launch_bounds__(256) void wprep_kernel(
    const float* __restrict__ w1, const float* __restrict__ w2,
    uint* __restrict__ wh1, uint* __restrict__ wl1,
    uint* __restrict__ wh2, uint* __restrict__ wl2)
{
    const int idx = blockIdx.x * 256 + threadIdx.x;      // 0..18431
    const float* w = blockIdx.y ? w2 : w1;
    uint* wh = blockIdx.y ? wh2 : wh1;
    uint* wl = blockIdx.y ? wl2 : wl1;
    const int tap = idx >> 11;           // 9
    const int oc  = (idx >> 5) & 63;     // 64
    const int icp = idx & 31;            // 32 ic-pairs (dword index)
    float w0 = w[(oc * 64 + 2 * icp) * 9 + tap];
    float w1v = w[(oc * 64 + 2 * icp + 1) * 9 + tap];
    uint h0 = bf16rne(w0); float l0 = w0 - bf16val(h0);
    uint h1 = bf16rne(w1v); float l1 = w1v - bf16val(h1);
    const int a = tap * 2048 + (icp >> 2) * 256 + oc * 4 + (icp & 3);
    wh[a] = h0 | (h1 << 16);
    wl[a] = bf16rne(l0) | (bf16rne(l1) << 16);
}

// ---------------- conv 3x3 reflect via MFMA, 4-row tile, LDS halo ----------
// wave w: Mtile mt = w&1 (32 oc), row-pair rq = w>>1 (rows rq*2, rq*2+1).
// MODE 1: input = fp32 NCHW x (fused repack, swizzle on ds_write).
//         PReLU + fragment-slot (hi) out.
// MODE 2: input = fragment-slot packed r1p (dense staged). hi out +
//         fused chan mean/max + fused gpool partials.
// Per tap: {8 ds_read_b128 + NEXT tap's 8 weight dwordx4} -> sched_barrier(0)
// -> 16 MFMA.
// launch_bounds (256,6): VGPR cap 85 (measured 80 fits), LDS 6x26112=157KB
// -> 6 blocks/CU = 24 waves/CU, 2x the latency-hiding pool of (256,3).
#define HPIX 204                 // 6*34 halo pixels
template<int MODE>
__global__ __launch_bounds__(256, 6) void conv_mfma(
    const float* __restrict__ xf,   // MODE 1: fp32 NCHW input
    const uint* __restrict__ xin,   // MODE 2: fragment-slot packed input
    const uint* __restrict__ wh, const uint* __restrict__ wl,
    const float* __restrict__ bias, const float* __restrict__ prelu,
    uint* __restrict__ op, float* __restrict__ amx, float* __restrict__ gsum)
{
    __shared__ uint lds[HPIX * 32];          // 26,112 B
    const int tid  = threadIdx.x;
    const int lane = tid & 63;
    const int wid  = tid >> 6;
    const int x0 = blockIdx.x * 32;
    const int y0 = blockIdx.y * 4;
    const int b  = blockIdx.z;
    const int colx = lane & 31;
    const int half = lane >> 5;
    const int mt = wid & 1;          // Mtile (oc group of 32)
    const int rq = wid >> 1;         // row pair: rows rq*2, rq*2+1

    // ---- stage halo
    if constexpr (MODE == 1) {
        // fused repack from fp32 NCHW: middle 32 cols
        const float* xb = xf + (size_t)b * CC * PLANE;
        const int cp = tid >> 3;       // channel pair 0..31
        const int q  = tid & 7;        // pixel quad 0..7
#pragma unroll
        for (int r = 0; r < 6; r++) {
            int gy = y0 - 1 + r; gy = gy < 0 ? 1 : (gy > 255 ? 254 : gy);
            const float* p0 = xb + (size_t)(2 * cp) * PLANE + gy * 256 + x0 + q * 4;
            const float4 a = *(const float4*)p0;
            const float4 c = *(const float4*)(p0 + PLANE);
            uint dd[4];
            dd[0] = bf16rne(a.x) | (bf16rne(c.x) << 16);
            dd[1] = bf16rne(a.y) | (bf16rne(c.y) << 16);
            dd[2] = bf16rne(a.z) | (bf16rne(c.z) << 16);
            dd[3] = bf16rne(a.w) | (bf16rne(c.w) << 16);
#pragma unroll
            for (int i = 0; i < 4; i++) {
                const int lpix = r * 34 + 1 + q * 4 + i;
                const int slot = (cp >> 2) ^ (lpix & 7);
                lds[(lpix * 8 + slot) * 4 + (cp & 3)] = dd[i];
            }
        }
        // edges: 6 rows x 2 cols x 32 cps
        if (tid < 192) {
            const int r = tid >> 5, cpe = tid & 31;
            int gy = y0 - 1 + r; gy = gy < 0 ? 1 : (gy > 255 ? 254 : gy);
#pragma unroll
            for (int e = 0; e < 2; e++) {
                int gx = e ? x0 + 32 : x0 - 1;
                gx = gx < 0 ? 1 : (gx > 255 ? 254 : gx);
                const float v0 = xb[(size_t)(2 * cpe) * PLANE + gy * 256 + gx];
                const float v1 = xb[(size_t)(2 * cpe + 1) * PLANE + gy * 256 + gx];
                const int lpix = r * 34 + (e ? 33 : 0);
                const int slot = (cpe >> 2) ^ (lpix & 7);
                lds[(lpix * 8 + slot) * 4 + (cpe & 3)] =
                    bf16rne(v0) | (bf16rne(v1) << 16);
            }
        }
    } else {
        // dense staged from fragment-slot packed input
        const uint* gb = xin + (size_t)b * PLANE * 32;
        uint4 st[6];
#pragma unroll
        for (int r = 0; r < 6; r++) {
            int gy = y0 - 1 + r; gy = gy < 0 ? 1 : (gy > 255 ? 254 : gy);
            st[r] = *(const uint4*)(gb + (size_t)(gy * 8 + (x0 >> 5)) * 1024 + tid * 4);
        }
        const int hcol = (tid & 31) + 1;
        const int c2s  = tid >> 5;
#pragma unroll
        for (int r = 0; r < 6; r++) {
            const int lpix = r * 34 + hcol;
            const int lslot = c2s ^ (lpix & 7);
            *(uint4*)&lds[(lpix * 8 + lslot) * 4] = st[r];
        }
        if (tid < 96) {
            const int r  = tid >> 4;
            const int e  = (tid >> 3) & 1;
            const int sl = tid & 7;
            int gy = y0 - 1 + r; gy = gy < 0 ? 1 : (gy > 255 ? 254 : gy);
            int gx = e ? x0 + 32 : x0 - 1;
            gx = gx < 0 ? 1 : (gx > 255 ? 254 : gx);
            const uint4 v = *(const uint4*)(gb + chunk_addr(gy * 256 + gx, sl));
            const int lpix = r * 34 + (e ? 33 : 0);
            const int lslot = sl ^ (lpix & 7);
            *(uint4*)&lds[(lpix * 8 + lslot) * 4] = v;
        }
    }

    // lane-dense weight base for this wave's Mtile; preload tap 0
    const uint* wbh = wh + half * 256 + (mt * 32 + colx) * 4;
    const uint* wbl = wl + half * 256 + (mt * 32 + colx) * 4;
    uint4 Hc[4], Lc[4];
#pragma unroll
    for (int c = 0; c < 4; c++) {
        Hc[c] = *(const uint4*)(wbh + c * 512);
        Lc[c] = *(const uint4*)(wbl + c * 512);
    }
    __syncthreads();

    f32x16 acc0 = (f32x16)0.f, acc1 = (f32x16)0.f;   // rows rq*2, rq*2+1

#pragma unroll
    for (int tap = 0; tap < 9; tap++) {
        const int dy = tap / 3, dx = tap % 3;
        const int pixb = (rq * 2 + dy) * 34 + dx + colx;   // row rq*2

        uint4 Ba[4], Bb[4];
#pragma unroll
        for (int c = 0; c < 4; c++) {
            const int c2 = c * 2 + half;
            const int p0 = pixb, p1 = pixb + 34;
            Ba[c] = *(const uint4*)&lds[(p0 * 8 + (c2 ^ (p0 & 7))) * 4];
            Bb[c] = *(const uint4*)&lds[(p1 * 8 + (c2 ^ (p1 & 7))) * 4];
        }
        uint4 Hn[4], Ln[4];
        if (tap < 8) {
#pragma unroll
            for (int c = 0; c < 4; c++) {
                Hn[c] = *(const uint4*)(wbh + (tap + 1) * 2048 + c * 512);
                Ln[c] = *(const uint4*)(wbl + (tap + 1) * 2048 + c * 512);
            }
        }
        __builtin_amdgcn_sched_barrier(0);
#pragma unroll
        for (int c = 0; c < 4; c++) {
            const s16x8 b0 = fragpack(Ba[c]), b1 = fragpack(Bb[c]);
            const s16x8 ah = fragpack(Hc[c]), al = fragpack(Lc[c]);
            acc0 = __builtin_amdgcn_mfma_f32_32x32x16_bf16(ah, b0, acc0, 0, 0, 0);
            acc1 = __builtin_amdgcn_mfma_f32_32x32x16_bf16(ah, b1, acc1, 0, 0, 0);
            acc0 = __builtin_amdgcn_mfma_f32_32x32x16_bf16(al, b0, acc0, 0, 0, 0);
            acc1 = __builtin_amdgcn_mfma_f32_32x32x16_bf16(al, b1, acc1, 0, 0, 0);
        }
        if (tap < 8) {
#pragma unroll
            for (int c = 0; c < 4; c++) { Hc[c] = Hn[c]; Lc[c] = Ln[c]; }
        }
    }

    // ---- epilogue. C/D layout (32x32): col=lane&31 (pixel), row=(j&3)+8*(j>>2)+4*half (oc)
    const int pcol = colx, seg = half;
    const int pixg = (y0 + wid) * 256 + x0 + pcol;
    __syncthreads();                    // halo reads done; reuse lds for transpose
#define STH(ACC, RR, DOPRELU) { \
    _Pragma("unroll") \
    for (int j = 0; j < 16; j += 2) { \
        const int row = (j & 3) + 8 * (j >> 2) + 4 * half; \
        const int oc = mt * 32 + row; \
        float v0 = ACC[j]     + bias[oc]; \
        float v1 = ACC[j + 1] + bias[oc + 1]; \
        if (DOPRELU) { \
            const float a0 = prelu[oc], a1 = prelu[oc + 1]; \
            v0 = fmaxf(v0, 0.f) + a0 * fminf(v0, 0.f); \
            v1 = fmaxf(v1, 0.f) + a1 * fminf(v1, 0.f); \
        } \
        const int icp = oc >> 1; \
        lds[((RR) * 32 + icp) * 32 + (colx ^ icp)] = \
            bf16rne(v0) | (bf16rne(v1) << 16); \
    } }
    STH(acc0, rq * 2, (MODE == 1)) STH(acc1, rq * 2 + 1, (MODE == 1))
#undef STH
    __syncthreads();
    uint d[16];
#pragma unroll
    for (int i = 0; i < 16; i++) {
        const int icp = seg * 16 + i;
        d[i] = lds[(wid * 32 + icp) * 32 + (pcol ^ icp)];
    }
    uint* o = op + (size_t)b * PLANE * 32 + chunk_addr(pixg, seg * 4);
#pragma unroll
    for (int k = 0; k < 4; k++)
        *(uint4*)(o + k * 128) = make_uint4(d[4*k], d[4*k+1], d[4*k+2], d[4*k+3]);

    if constexpr (MODE == 2) {
        float s_ = 0.f, m_ = -INFINITY;
#pragma unroll
        for (int i = 0; i < 16; i++) {
            float ve = bf16val(d[i] & 0xffffu);
            float vo = bf16val(d[i] >> 16);
            s_ += ve + vo;
            m_ = fmaxf(m_, fmaxf(ve, vo));
        }
        const int cp_g = tid & 31;
        const int hr_g = tid >> 5;
        const int row_g = hr_g >> 1;
        const int pc0_g = (hr_g & 1) * 16;
        float gs0 = 0.f, gs1 = 0.f;
#pragma unroll
        for (int p = 0; p < 16; p++) {
            const int pc = pc0_g + p;
            const uint v = lds[(row_g * 32 + cp_g) * 32 + (pc ^ cp_g)];
            gs0 += bf16val(v & 0xffffu);
            gs1 += bf16val(v >> 16);
        }
        s_ += __shfl_xor(s_, 32, 64);
        m_ = fmaxf(m_, __shfl_xor(m_, 32, 64));
        if (seg == 0) {
            amx[(size_t)b * 2 * PLANE + pixg] = s_ * (1.f / 64.f);
            amx[(size_t)b * 2 * PLANE + PLANE + pixg] = m_;
        }
        __syncthreads();
        lds[4096 + hr_g * 64 + 2 * cp_g]     = __float_as_uint(gs0);
        lds[4096 + hr_g * 64 + 2 * cp_g + 1] = __float_as_uint(gs1);
        __syncthreads();
        if (tid < 64) {
            float t = 0.f;
#pragma unroll
            for (int h8 = 0; h8 < 8; h8++)
                t += __uint_as_float(lds[4096 + h8 * 64 + tid]);
            atomicAdd(&gsum[b * 64 + tid], t * (1.f / PLANE));
        }
    }
}

// ---------------- tiny MLPs -> hyper kernels, fragment-slot hi/lo --------
__global__ __launch_bounds__(256) void mlp_kernel(
    const float* __restrict__ h, const float* __restrict__ g,
    const float* __restrict__ ca_w1, const float* __restrict__ ca_b1,
    const float* __restrict__ ca_a,
    const float* __restrict__ ca_w2, const float* __restrict__ ca_b2,
    const float* __restrict__ fc_w, const float* __restrict__ fc_b,
    const float* __restrict__ k1_w, const float* __restrict__ k1_b,
    const float* __restrict__ k2_w, const float* __restrict__ k2_b,
    const float* __restrict__ k3_w, const float* __restrict__ k3_b,
    uint* __restrict__ kAhi, uint* __restrict__ kAlo,
    uint* __restrict__ kBhi, uint* __restrict__ kBlo)
{
    int b = blockIdx.x, tid = threadIdx.x;
    __shared__ float gb[64], t16[16], u32[32], v32[32], cg1[32], casig[64];

    if (tid < 64) gb[tid] = g[b * 64 + tid];
    __syncthreads();

    if (tid < 16) {
        float s = fc_b[tid];
        for (int j = 0; j < 16; j++) s += fc_w[tid * 16 + j] * h[b * 16 + j];
        t16[tid] = s >= 0.f ? s : 0.01f * s;
    }
    if (tid < 32) {
        float c1 = ca_b1[tid];
        for (int j = 0; j < 64; j++) c1 += ca_w1[tid * 64 + j] * gb[j];
        cg1[tid] = fmaxf(c1, 0.f) + ca_a[tid] * fminf(c1, 0.f);
    }
    __syncthreads();
    if (tid < 32) {
        float s = k1_b[tid];
        for (int j = 0; j < 16; j++) s += k1_w[tid * 16 + j] * t16[j];
        u32[tid] = s >= 0.f ? s : 0.01f * s;
    }
    if (tid < 64) {
        float c2 = ca_b2[tid];
        for (int j = 0; j < 32; j++) c2 += ca_w2[tid * 32 + j] * cg1[j];
        casig[tid] = 1.f / (1.f + expf(-c2));
    }
    __syncthreads();
    if (tid < 32) {
        float s = k2_b[tid];
        for (int j = 0; j < 32; j++) s += k2_w[tid * 32 + j] * u32[j];
        v32[tid] = s >= 0.f ? s : 0.01f * s;
    }
    __syncthreads();
    // k3: 8192 outputs, adjacent pairs -> one packed dword, fragment-slot store
    for (int o2 = tid; o2 < 4096; o2 += 256) {
        const int o = o2 * 2;
        const int oc = o >> 7;        // /128
        const int i = o & 127;        // even
        float s0 = k3_b[o], s1 = k3_b[o + 1];
        for (int j = 0; j < 32; j++) {
            s0 += k3_w[(size_t)o * 32 + j] * v32[j];
            s1 += k3_w[(size_t)(o + 1) * 32 + j] * v32[j];
        }
        uint *hi, *lo;
        if (i < 64) { hi = kAhi; lo = kAlo; }
        else { s0 *= casig[i - 64]; s1 *= casig[i - 63]; hi = kBhi; lo = kBlo; }
        const int cp = (i & 63) >> 1;
        uint h0 = bf16rne(s0); float l0 = s0 - bf16val(h0);
        uint h1 = bf16rne(s1); float l1 = s1 - bf16val(h1);
        const size_t a = (size_t)b * 2048 + (cp >> 2) * 256 + oc * 4 + (cp & 3);
        hi[a] = h0 | (h1 << 16);
        lo[a] = bf16rne(l0) | (bf16rne(l1) << 16);
    }
}

// ---------------- final via MFMA + inlined spatial-attention conv -----------
// out = x + hcb + sig(sa3x3(amx))*(A.r) + (B.r);  r = hi only
__global__ __launch_bounds__(256, 8) void final_mfma(
    const float* __restrict__ x, const uint* __restrict__ rph,
    const float* __restrict__ amx,
    const uint* __restrict__ kAhi, const uint* __restrict__ kAlo,
    const uint* __restrict__ kBhi, const uint* __restrict__ kBlo,
    const float* __restrict__ sa_w, const float* __restrict__ sa_b,
    const float* __restrict__ hcb, float* __restrict__ out)
{
    const int tid = threadIdx.x;
    const int lane = tid & 63;
    const int wid = tid >> 6;
    const int mt = wid & 1;          // oc Mtile
    const int gq = wid >> 1;         // pixel group
    const int b = blockIdx.y;
    const int colx = lane & 31;
    const int half = lane >> 5;
    const int pix = blockIdx.x * 64 + gq * 32 + colx;
    const int pgroup = blockIdx.x * 2 + gq;   // pix >> 5

    const size_t kb = (size_t)b * 2048 + half * 256 + (size_t)(mt * 32 + colx) * 4;
    uint4 KAh[4], KAl[4], KBh[4], KBl[4];
#pragma unroll
    for (int c = 0; c < 4; c++) {
        KAh[c] = *(const uint4*)(kAhi + kb + c * 512);
        KAl[c] = *(const uint4*)(kAlo + kb + c * 512);
        KBh[c] = *(const uint4*)(kBhi + kb + c * 512);
        KBl[c] = *(const uint4*)(kBlo + kb + c * 512);
    }
    const size_t rb = (size_t)b * PLANE * 32 + (size_t)pgroup * 1024
                    + half * 128 + colx * 4;
    uint4 Bh[4];
#pragma unroll
    for (int c = 0; c < 4; c++)
        Bh[c] = *(const uint4*)(rph + rb + c * 256);

    const int xx = pix & 255, yy = pix >> 8;
    float sacc = sa_b[0];
    const float* ab = amx + (size_t)b * 2 * PLANE;
#pragma unroll
    for (int cc = 0; cc < 2; cc++)
#pragma unroll
        for (int dy2 = -1; dy2 <= 1; dy2++)
#pragma unroll
            for (int dx2 = -1; dx2 <= 1; dx2++) {
                int gx = xx + dx2; gx = gx < 0 ? 1 : (gx >= WW ? 2 * WW - 2 - gx : gx);
                int gy = yy + dy2; gy = gy < 0 ? 1 : (gy >= HH ? 2 * HH - 2 - gy : gy);
                sacc += sa_w[cc * 9 + (dy2 + 1) * 3 + (dx2 + 1)]
                      * ab[(size_t)cc * PLANE + gy * WW + gx];
            }
    const float sig = 1.f / (1.f + expf(-sacc));

    f32x16 accA = (f32x16)0.f, accB = (f32x16)0.f;
#pragma unroll
    for (int c = 0; c < 4; c++) {
        const s16x8 bh = fragpack(Bh[c]);
        const s16x8 ah = fragpack(KAh[c]), al = fragpack(KAl[c]);
        const s16x8 ch = fragpack(KBh[c]), cl = fragpack(KBl[c]);
        accA = __builtin_amdgcn_mfma_f32_32x32x16_bf16(ah, bh, accA, 0, 0, 0);
        accA = __builtin_amdgcn_mfma_f32_32x32x16_bf16(al, bh, accA, 0, 0, 0);
        accB = __builtin_amdgcn_mfma_f32_32x32x16_bf16(ch, bh, accB, 0, 0, 0);
        accB = __builtin_amdgcn_mfma_f32_32x32x16_bf16(cl, bh, accB, 0, 0, 0);
    }
#pragma unroll
    for (int j = 0; j < 16; j++) {
        const int row = (j & 3) + 8 * (j >> 2) + 4 * half;
        const int oc = mt * 32 + row;
        const size_t idx = ((size_t)b * 64 + oc) * PLANE + pix;
        out[idx] = x[idx] + hcb[oc] + sig * accA[j] + accB[j];
    }
}

extern "C" void kernel_launch(void* const* d_in, const int* in_sizes, int n_in,
                              void* d_out, int out_size, void* d_ws, size_t ws_size,
                              hipStream_t stream) {
    const float* x   = (const float*)d_in[0];
    const float* h   = (const float*)d_in[1];
    const float* c1w = (const float*)d_in[2];
    const float* c1b = (const float*)d_in[3];
    const float* pa  = (const float*)d_in[4];
    const float* c2w = (const float*)d_in[5];
    const float* c2b = (const float*)d_in[6];
    const float* saw = (const float*)d_in[7];
    const float* sab = (const float*)d_in[8];
    const float* cw1 = (const float*)d_in[9];
    const float* cb1 = (const float*)d_in[10];
    const float* caa = (const float*)d_in[11];
    const float* cw2 = (const float*)d_in[12];
    const float* cb2 = (const float*)d_in[13];
    const float* fcw = (const float*)d_in[14];
    const float* fcb = (const float*)d_in[15];
    const float* k1w = (const float*)d_in[16];
    const float* k1b = (const float*)d_in[17];
    const float* k2w = (const float*)d_in[18];
    const float* k2b = (const float*)d_in[19];
    const float* k3w = (const float*)d_in[20];
    const float* k3b = (const float*)d_in[21];
    const float* hcb = (const float*)d_in[22];
    float* out = (float*)d_out;

    char* ws = (char*)d_ws;
    const size_t SZ_Q = (size_t)8 * PLANE * 32 * 4;   // 67,108,864 (packed)
    uint*  r1p = (uint*)(ws + SZ_Q);                  // conv1 out (hi)
    uint*  rph = (uint*)(ws + 2 * SZ_Q);              // conv2 out hi
    float* amx   = (float*)ws;                        // region [0,SZ_Q) free
    uint*  kAhi  = (uint*)(ws + (size_t)8 * 3 * PLANE * 4 + 4096);
    uint*  kAlo  = kAhi + 8 * 2048;
    uint*  kBhi  = kAlo + 8 * 2048;
    uint*  kBlo  = kBhi + 8 * 2048;

    // weight packs + g live in d_out (dead until final_mfma overwrites it)
    uint* wsp = (uint*)d_out;
    uint* wh1 = wsp;          uint* wl1 = wsp + 18432;
    uint* wh2 = wsp + 36864;  uint* wl2 = wsp + 55296;
    float* g  = (float*)(wsp + 73728);                // 512 floats in d_out

    wprep_kernel<<<dim3(72, 2), 256, 0, stream>>>(c1w, c2w, wh1, wl1, wh2, wl2);
    hipMemsetAsync(g, 0, 512 * sizeof(float), stream);

    dim3 cgrid(WW / 32, HH / 4, 8);  // (8, 64, 8)
    conv_mfma<1><<<cgrid, 256, 0, stream>>>(x, nullptr, wh1, wl1, c1b, pa, r1p,
                                            nullptr, nullptr);
    conv_mfma<2><<<cgrid, 256, 0, stream>>>(nullptr, r1p, wh2, wl2, c2b, nullptr,
                                            rph, amx, g);

    mlp_kernel<<<8, 256, 0, stream>>>(h, g, cw1, cb1, caa, cw2, cb2,
                                      fcw, fcb, k1w, k1b, k2w, k2b, k3w, k3b,
                                      kAhi, kAlo, kBhi, kBlo);
    final_mfma<<<dim3(PLANE / 64, 8), 256, 0, stream>>>(
        x, rph, amx, kAhi, kAlo, kBhi, kBlo, saw, sab, hcb, out);
}

// Round 20
// 720.348 us; speedup vs baseline: 1.7640x; 1.7640x over previous
//
#include <hip/hip_runtime.h>
#include <math.h>

#define HH 256
#define WW 256
#define CC 64
#define PLANE (HH*WW)

typedef short s16x8 __attribute__((ext_vector_type(8)));
typedef float f32x16 __attribute__((ext_vector_type(16)));
typedef unsigned int uint;
typedef uint u32x4v __attribute__((ext_vector_type(4)));

__device__ inline uint bf16rne(float f) {
    uint u = __float_as_uint(f);
    return (u + 0x7FFFu + ((u >> 16) & 1u)) >> 16;
}
__device__ inline float bf16val(uint h) { return __uint_as_float(h << 16); }
__device__ inline s16x8 fragpack(uint4 q) {
    u32x4v t = {q.x, q.y, q.z, q.w};
    return __builtin_bit_cast(s16x8, t);
}
// activation fragment-slot layout: dword (pix, dwi) at
//   (pix>>5)*1024 + (dwi>>2)*128 + (pix&31)*4 + (dwi&3)
__device__ inline size_t chunk_addr(int pix, int c2) {
    return (size_t)(pix >> 5) * 1024 + c2 * 128 + (pix & 31) * 4;
}
// weight fragment-slot layout: dword (tap, oc, dwi) at
//   tap*2048 + (dwi>>2)*256 + oc*4 + (dwi&3)   -> lane-dense dwordx4 loads

// ---------------- weight prep: split fp32 W into bf16 hi/lo ----------------
__global__ __launch_bounds__(256) void wprep_kernel(
    const float* __restrict__ w1, const float* __restrict__ w2,
    uint* __restrict__ wh1, uint* __restrict__ wl1,
    uint* __restrict__ wh2, uint* __restrict__ wl2)
{
    const int idx = blockIdx.x * 256 + threadIdx.x;      // 0..18431
    const float* w = blockIdx.y ? w2 : w1;
    uint* wh = blockIdx.y ? wh2 : wh1;
    uint* wl = blockIdx.y ? wl2 : wl1;
    const int tap = idx >> 11;           // 9
    const int oc  = (idx >> 5) & 63;     // 64
    const int icp = idx & 31;            // 32 ic-pairs (dword index)
    float w0 = w[(oc * 64 + 2 * icp) * 9 + tap];
    float w1v = w[(oc * 64 + 2 * icp + 1) * 9 + tap];
    uint h0 = bf16rne(w0); float l0 = w0 - bf16val(h0);
    uint h1 = bf16rne(w1v); float l1 = w1v - bf16val(h1);
    const int a = tap * 2048 + (icp >> 2) * 256 + oc * 4 + (icp & 3);
    wh[a] = h0 | (h1 << 16);
    wl[a] = bf16rne(l0) | (bf16rne(l1) << 16);
}

// ---------------- conv 3x3 reflect via MFMA, 4-row tile, LDS halo ----------
// wave w: Mtile mt = w&1 (32 oc), row-pair rq = w>>1 (rows rq*2, rq*2+1).
// MODE 1: input = fp32 NCHW x (fused repack, swizzle on ds_write).
//         PReLU + fragment-slot (hi) out.
// MODE 2: input = fragment-slot packed r1p (dense staged). hi out +
//         fused chan mean/max + fused gpool partials.
// Per tap: {8 ds_read_b128 + NEXT tap's 8 weight dwordx4} -> sched_barrier(0)
// -> 16 MFMA.
// launch_bounds (256,4): VGPR cap 128 >> measured 80 (allocator unconstrained;
// (256,6) capped at 85 and spilled acc to scratch -> 1.3 GB scratch writes).
#define HPIX 204                 // 6*34 halo pixels
template<int MODE>
__global__ __launch_bounds__(256, 4) void conv_mfma(
    const float* __restrict__ xf,   // MODE 1: fp32 NCHW input
    const uint* __restrict__ xin,   // MODE 2: fragment-slot packed input
    const uint* __restrict__ wh, const uint* __restrict__ wl,
    const float* __restrict__ bias, const float* __restrict__ prelu,
    uint* __restrict__ op, float* __restrict__ amx, float* __restrict__ gsum)
{
    __shared__ uint lds[HPIX * 32];          // 26,112 B
    const int tid  = threadIdx.x;
    const int lane = tid & 63;
    const int wid  = tid >> 6;
    const int x0 = blockIdx.x * 32;
    const int y0 = blockIdx.y * 4;
    const int b  = blockIdx.z;
    const int colx = lane & 31;
    const int half = lane >> 5;
    const int mt = wid & 1;          // Mtile (oc group of 32)
    const int rq = wid >> 1;         // row pair: rows rq*2, rq*2+1

    // ---- stage halo
    if constexpr (MODE == 1) {
        // fused repack from fp32 NCHW: middle 32 cols
        const float* xb = xf + (size_t)b * CC * PLANE;
        const int cp = tid >> 3;       // channel pair 0..31
        const int q  = tid & 7;        // pixel quad 0..7
#pragma unroll
        for (int r = 0; r < 6; r++) {
            int gy = y0 - 1 + r; gy = gy < 0 ? 1 : (gy > 255 ? 254 : gy);
            const float* p0 = xb + (size_t)(2 * cp) * PLANE + gy * 256 + x0 + q * 4;
            const float4 a = *(const float4*)p0;
            const float4 c = *(const float4*)(p0 + PLANE);
            uint dd[4];
            dd[0] = bf16rne(a.x) | (bf16rne(c.x) << 16);
            dd[1] = bf16rne(a.y) | (bf16rne(c.y) << 16);
            dd[2] = bf16rne(a.z) | (bf16rne(c.z) << 16);
            dd[3] = bf16rne(a.w) | (bf16rne(c.w) << 16);
#pragma unroll
            for (int i = 0; i < 4; i++) {
                const int lpix = r * 34 + 1 + q * 4 + i;
                const int slot = (cp >> 2) ^ (lpix & 7);
                lds[(lpix * 8 + slot) * 4 + (cp & 3)] = dd[i];
            }
        }
        // edges: 6 rows x 2 cols x 32 cps
        if (tid < 192) {
            const int r = tid >> 5, cpe = tid & 31;
            int gy = y0 - 1 + r; gy = gy < 0 ? 1 : (gy > 255 ? 254 : gy);
#pragma unroll
            for (int e = 0; e < 2; e++) {
                int gx = e ? x0 + 32 : x0 - 1;
                gx = gx < 0 ? 1 : (gx > 255 ? 254 : gx);
                const float v0 = xb[(size_t)(2 * cpe) * PLANE + gy * 256 + gx];
                const float v1 = xb[(size_t)(2 * cpe + 1) * PLANE + gy * 256 + gx];
                const int lpix = r * 34 + (e ? 33 : 0);
                const int slot = (cpe >> 2) ^ (lpix & 7);
                lds[(lpix * 8 + slot) * 4 + (cpe & 3)] =
                    bf16rne(v0) | (bf16rne(v1) << 16);
            }
        }
    } else {
        // dense staged from fragment-slot packed input
        const uint* gb = xin + (size_t)b * PLANE * 32;
        uint4 st[6];
#pragma unroll
        for (int r = 0; r < 6; r++) {
            int gy = y0 - 1 + r; gy = gy < 0 ? 1 : (gy > 255 ? 254 : gy);
            st[r] = *(const uint4*)(gb + (size_t)(gy * 8 + (x0 >> 5)) * 1024 + tid * 4);
        }
        const int hcol = (tid & 31) + 1;
        const int c2s  = tid >> 5;
#pragma unroll
        for (int r = 0; r < 6; r++) {
            const int lpix = r * 34 + hcol;
            const int lslot = c2s ^ (lpix & 7);
            *(uint4*)&lds[(lpix * 8 + lslot) * 4] = st[r];
        }
        if (tid < 96) {
            const int r  = tid >> 4;
            const int e  = (tid >> 3) & 1;
            const int sl = tid & 7;
            int gy = y0 - 1 + r; gy = gy < 0 ? 1 : (gy > 255 ? 254 : gy);
            int gx = e ? x0 + 32 : x0 - 1;
            gx = gx < 0 ? 1 : (gx > 255 ? 254 : gx);
            const uint4 v = *(const uint4*)(gb + chunk_addr(gy * 256 + gx, sl));
            const int lpix = r * 34 + (e ? 33 : 0);
            const int lslot = sl ^ (lpix & 7);
            *(uint4*)&lds[(lpix * 8 + lslot) * 4] = v;
        }
    }

    // lane-dense weight base for this wave's Mtile; preload tap 0
    const uint* wbh = wh + half * 256 + (mt * 32 + colx) * 4;
    const uint* wbl = wl + half * 256 + (mt * 32 + colx) * 4;
    uint4 Hc[4], Lc[4];
#pragma unroll
    for (int c = 0; c < 4; c++) {
        Hc[c] = *(const uint4*)(wbh + c * 512);
        Lc[c] = *(const uint4*)(wbl + c * 512);
    }
    __syncthreads();

    f32x16 acc0 = (f32x16)0.f, acc1 = (f32x16)0.f;   // rows rq*2, rq*2+1

#pragma unroll
    for (int tap = 0; tap < 9; tap++) {
        const int dy = tap / 3, dx = tap % 3;
        const int pixb = (rq * 2 + dy) * 34 + dx + colx;   // row rq*2

        uint4 Ba[4], Bb[4];
#pragma unroll
        for (int c = 0; c < 4; c++) {
            const int c2 = c * 2 + half;
            const int p0 = pixb, p1 = pixb + 34;
            Ba[c] = *(const uint4*)&lds[(p0 * 8 + (c2 ^ (p0 & 7))) * 4];
            Bb[c] = *(const uint4*)&lds[(p1 * 8 + (c2 ^ (p1 & 7))) * 4];
        }
        uint4 Hn[4], Ln[4];
        if (tap < 8) {
#pragma unroll
            for (int c = 0; c < 4; c++) {
                Hn[c] = *(const uint4*)(wbh + (tap + 1) * 2048 + c * 512);
                Ln[c] = *(const uint4*)(wbl + (tap + 1) * 2048 + c * 512);
            }
        }
        __builtin_amdgcn_sched_barrier(0);
#pragma unroll
        for (int c = 0; c < 4; c++) {
            const s16x8 b0 = fragpack(Ba[c]), b1 = fragpack(Bb[c]);
            const s16x8 ah = fragpack(Hc[c]), al = fragpack(Lc[c]);
            acc0 = __builtin_amdgcn_mfma_f32_32x32x16_bf16(ah, b0, acc0, 0, 0, 0);
            acc1 = __builtin_amdgcn_mfma_f32_32x32x16_bf16(ah, b1, acc1, 0, 0, 0);
            acc0 = __builtin_amdgcn_mfma_f32_32x32x16_bf16(al, b0, acc0, 0, 0, 0);
            acc1 = __builtin_amdgcn_mfma_f32_32x32x16_bf16(al, b1, acc1, 0, 0, 0);
        }
        if (tap < 8) {
#pragma unroll
            for (int c = 0; c < 4; c++) { Hc[c] = Hn[c]; Lc[c] = Ln[c]; }
        }
    }

    // ---- epilogue. C/D layout (32x32): col=lane&31 (pixel), row=(j&3)+8*(j>>2)+4*half (oc)
    const int pcol = colx, seg = half;
    const int pixg = (y0 + wid) * 256 + x0 + pcol;
    __syncthreads();                    // halo reads done; reuse lds for transpose
#define STH(ACC, RR, DOPRELU) { \
    _Pragma("unroll") \
    for (int j = 0; j < 16; j += 2) { \
        const int row = (j & 3) + 8 * (j >> 2) + 4 * half; \
        const int oc = mt * 32 + row; \
        float v0 = ACC[j]     + bias[oc]; \
        float v1 = ACC[j + 1] + bias[oc + 1]; \
        if (DOPRELU) { \
            const float a0 = prelu[oc], a1 = prelu[oc + 1]; \
            v0 = fmaxf(v0, 0.f) + a0 * fminf(v0, 0.f); \
            v1 = fmaxf(v1, 0.f) + a1 * fminf(v1, 0.f); \
        } \
        const int icp = oc >> 1; \
        lds[((RR) * 32 + icp) * 32 + (colx ^ icp)] = \
            bf16rne(v0) | (bf16rne(v1) << 16); \
    } }
    STH(acc0, rq * 2, (MODE == 1)) STH(acc1, rq * 2 + 1, (MODE == 1))
#undef STH
    __syncthreads();
    uint d[16];
#pragma unroll
    for (int i = 0; i < 16; i++) {
        const int icp = seg * 16 + i;
        d[i] = lds[(wid * 32 + icp) * 32 + (pcol ^ icp)];
    }
    uint* o = op + (size_t)b * PLANE * 32 + chunk_addr(pixg, seg * 4);
#pragma unroll
    for (int k = 0; k < 4; k++)
        *(uint4*)(o + k * 128) = make_uint4(d[4*k], d[4*k+1], d[4*k+2], d[4*k+3]);

    if constexpr (MODE == 2) {
        float s_ = 0.f, m_ = -INFINITY;
#pragma unroll
        for (int i = 0; i < 16; i++) {
            float ve = bf16val(d[i] & 0xffffu);
            float vo = bf16val(d[i] >> 16);
            s_ += ve + vo;
            m_ = fmaxf(m_, fmaxf(ve, vo));
        }
        const int cp_g = tid & 31;
        const int hr_g = tid >> 5;
        const int row_g = hr_g >> 1;
        const int pc0_g = (hr_g & 1) * 16;
        float gs0 = 0.f, gs1 = 0.f;
#pragma unroll
        for (int p = 0; p < 16; p++) {
            const int pc = pc0_g + p;
            const uint v = lds[(row_g * 32 + cp_g) * 32 + (pc ^ cp_g)];
            gs0 += bf16val(v & 0xffffu);
            gs1 += bf16val(v >> 16);
        }
        s_ += __shfl_xor(s_, 32, 64);
        m_ = fmaxf(m_, __shfl_xor(m_, 32, 64));
        if (seg == 0) {
            amx[(size_t)b * 2 * PLANE + pixg] = s_ * (1.f / 64.f);
            amx[(size_t)b * 2 * PLANE + PLANE + pixg] = m_;
        }
        __syncthreads();
        lds[4096 + hr_g * 64 + 2 * cp_g]     = __float_as_uint(gs0);
        lds[4096 + hr_g * 64 + 2 * cp_g + 1] = __float_as_uint(gs1);
        __syncthreads();
        if (tid < 64) {
            float t = 0.f;
#pragma unroll
            for (int h8 = 0; h8 < 8; h8++)
                t += __uint_as_float(lds[4096 + h8 * 64 + tid]);
            atomicAdd(&gsum[b * 64 + tid], t * (1.f / PLANE));
        }
    }
}

// ---------------- tiny MLPs -> hyper kernels, fragment-slot hi/lo --------
__global__ __launch_bounds__(256) void mlp_kernel(
    const float* __restrict__ h, const float* __restrict__ g,
    const float* __restrict__ ca_w1, const float* __restrict__ ca_b1,
    const float* __restrict__ ca_a,
    const float* __restrict__ ca_w2, const float* __restrict__ ca_b2,
    const float* __restrict__ fc_w, const float* __restrict__ fc_b,
    const float* __restrict__ k1_w, const float* __restrict__ k1_b,
    const float* __restrict__ k2_w, const float* __restrict__ k2_b,
    const float* __restrict__ k3_w, const float* __restrict__ k3_b,
    uint* __restrict__ kAhi, uint* __restrict__ kAlo,
    uint* __restrict__ kBhi, uint* __restrict__ kBlo)
{
    int b = blockIdx.x, tid = threadIdx.x;
    __shared__ float gb[64], t16[16], u32[32], v32[32], cg1[32], casig[64];

    if (tid < 64) gb[tid] = g[b * 64 + tid];
    __syncthreads();

    if (tid < 16) {
        float s = fc_b[tid];
        for (int j = 0; j < 16; j++) s += fc_w[tid * 16 + j] * h[b * 16 + j];
        t16[tid] = s >= 0.f ? s : 0.01f * s;
    }
    if (tid < 32) {
        float c1 = ca_b1[tid];
        for (int j = 0; j < 64; j++) c1 += ca_w1[tid * 64 + j] * gb[j];
        cg1[tid] = fmaxf(c1, 0.f) + ca_a[tid] * fminf(c1, 0.f);
    }
    __syncthreads();
    if (tid < 32) {
        float s = k1_b[tid];
        for (int j = 0; j < 16; j++) s += k1_w[tid * 16 + j] * t16[j];
        u32[tid] = s >= 0.f ? s : 0.01f * s;
    }
    if (tid < 64) {
        float c2 = ca_b2[tid];
        for (int j = 0; j < 32; j++) c2 += ca_w2[tid * 32 + j] * cg1[j];
        casig[tid] = 1.f / (1.f + expf(-c2));
    }
    __syncthreads();
    if (tid < 32) {
        float s = k2_b[tid];
        for (int j = 0; j < 32; j++) s += k2_w[tid * 32 + j] * u32[j];
        v32[tid] = s >= 0.f ? s : 0.01f * s;
    }
    __syncthreads();
    // k3: 8192 outputs, adjacent pairs -> one packed dword, fragment-slot store
    for (int o2 = tid; o2 < 4096; o2 += 256) {
        const int o = o2 * 2;
        const int oc = o >> 7;        // /128
        const int i = o & 127;        // even
        float s0 = k3_b[o], s1 = k3_b[o + 1];
        for (int j = 0; j < 32; j++) {
            s0 += k3_w[(size_t)o * 32 + j] * v32[j];
            s1 += k3_w[(size_t)(o + 1) * 32 + j] * v32[j];
        }
        uint *hi, *lo;
        if (i < 64) { hi = kAhi; lo = kAlo; }
        else { s0 *= casig[i - 64]; s1 *= casig[i - 63]; hi = kBhi; lo = kBlo; }
        const int cp = (i & 63) >> 1;
        uint h0 = bf16rne(s0); float l0 = s0 - bf16val(h0);
        uint h1 = bf16rne(s1); float l1 = s1 - bf16val(h1);
        const size_t a = (size_t)b * 2048 + (cp >> 2) * 256 + oc * 4 + (cp & 3);
        hi[a] = h0 | (h1 << 16);
        lo[a] = bf16rne(l0) | (bf16rne(l1) << 16);
    }
}

// ---------------- final via MFMA + inlined spatial-attention conv -----------
// out = x + hcb + sig(sa3x3(amx))*(A.r) + (B.r);  r = hi only
__global__ __launch_bounds__(256, 8) void final_mfma(
    const float* __restrict__ x, const uint* __restrict__ rph,
    const float* __restrict__ amx,
    const uint* __restrict__ kAhi, const uint* __restrict__ kAlo,
    const uint* __restrict__ kBhi, const uint* __restrict__ kBlo,
    const float* __restrict__ sa_w, const float* __restrict__ sa_b,
    const float* __restrict__ hcb, float* __restrict__ out)
{
    const int tid = threadIdx.x;
    const int lane = tid & 63;
    const int wid = tid >> 6;
    const int mt = wid & 1;          // oc Mtile
    const int gq = wid >> 1;         // pixel group
    const int b = blockIdx.y;
    const int colx = lane & 31;
    const int half = lane >> 5;
    const int pix = blockIdx.x * 64 + gq * 32 + colx;
    const int pgroup = blockIdx.x * 2 + gq;   // pix >> 5

    const size_t kb = (size_t)b * 2048 + half * 256 + (size_t)(mt * 32 + colx) * 4;
    uint4 KAh[4], KAl[4], KBh[4], KBl[4];
#pragma unroll
    for (int c = 0; c < 4; c++) {
        KAh[c] = *(const uint4*)(kAhi + kb + c * 512);
        KAl[c] = *(const uint4*)(kAlo + kb + c * 512);
        KBh[c] = *(const uint4*)(kBhi + kb + c * 512);
        KBl[c] = *(const uint4*)(kBlo + kb + c * 512);
    }
    const size_t rb = (size_t)b * PLANE * 32 + (size_t)pgroup * 1024
                    + half * 128 + colx * 4;
    uint4 Bh[4];
#pragma unroll
    for (int c = 0; c < 4; c++)
        Bh[c] = *(const uint4*)(rph + rb + c * 256);

    const int xx = pix & 255, yy = pix >> 8;
    float sacc = sa_b[0];
    const float* ab = amx + (size_t)b * 2 * PLANE;
#pragma unroll
    for (int cc = 0; cc < 2; cc++)
#pragma unroll
        for (int dy2 = -1; dy2 <= 1; dy2++)
#pragma unroll
            for (int dx2 = -1; dx2 <= 1; dx2++) {
                int gx = xx + dx2; gx = gx < 0 ? 1 : (gx >= WW ? 2 * WW - 2 - gx : gx);
                int gy = yy + dy2; gy = gy < 0 ? 1 : (gy >= HH ? 2 * HH - 2 - gy : gy);
                sacc += sa_w[cc * 9 + (dy2 + 1) * 3 + (dx2 + 1)]
                      * ab[(size_t)cc * PLANE + gy * WW + gx];
            }
    const float sig = 1.f / (1.f + expf(-sacc));

    f32x16 accA = (f32x16)0.f, accB = (f32x16)0.f;
#pragma unroll
    for (int c = 0; c < 4; c++) {
        const s16x8 bh = fragpack(Bh[c]);
        const s16x8 ah = fragpack(KAh[c]), al = fragpack(KAl[c]);
        const s16x8 ch = fragpack(KBh[c]), cl = fragpack(KBl[c]);
        accA = __builtin_amdgcn_mfma_f32_32x32x16_bf16(ah, bh, accA, 0, 0, 0);
        accA = __builtin_amdgcn_mfma_f32_32x32x16_bf16(al, bh, accA, 0, 0, 0);
        accB = __builtin_amdgcn_mfma_f32_32x32x16_bf16(ch, bh, accB, 0, 0, 0);
        accB = __builtin_amdgcn_mfma_f32_32x32x16_bf16(cl, bh, accB, 0, 0, 0);
    }
#pragma unroll
    for (int j = 0; j < 16; j++) {
        const int row = (j & 3) + 8 * (j >> 2) + 4 * half;
        const int oc = mt * 32 + row;
        const size_t idx = ((size_t)b * 64 + oc) * PLANE + pix;
        out[idx] = x[idx] + hcb[oc] + sig * accA[j] + accB[j];
    }
}

extern "C" void kernel_launch(void* const* d_in, const int* in_sizes, int n_in,
                              void* d_out, int out_size, void* d_ws, size_t ws_size,
                              hipStream_t stream) {
    const float* x   = (const float*)d_in[0];
    const float* h   = (const float*)d_in[1];
    const float* c1w = (const float*)d_in[2];
    const float* c1b = (const float*)d_in[3];
    const float* pa  = (const float*)d_in[4];
    const float* c2w = (const float*)d_in[5];
    const float* c2b = (const float*)d_in[6];
    const float* saw = (const float*)d_in[7];
    const float* sab = (const float*)d_in[8];
    const float* cw1 = (const float*)d_in[9];
    const float* cb1 = (const float*)d_in[10];
    const float* caa = (const float*)d_in[11];
    const float* cw2 = (const float*)d_in[12];
    const float* cb2 = (const float*)d_in[13];
    const float* fcw = (const float*)d_in[14];
    const float* fcb = (const float*)d_in[15];
    const float* k1w = (const float*)d_in[16];
    const float* k1b = (const float*)d_in[17];
    const float* k2w = (const float*)d_in[18];
    const float* k2b = (const float*)d_in[19];
    const float* k3w = (const float*)d_in[20];
    const float* k3b = (const float*)d_in[21];
    const float* hcb = (const float*)d_in[22];
    float* out = (float*)d_out;

    char* ws = (char*)d_ws;
    const size_t SZ_Q = (size_t)8 * PLANE * 32 * 4;   // 67,108,864 (packed)
    uint*  r1p = (uint*)(ws + SZ_Q);                  // conv1 out (hi)
    uint*  rph = (uint*)(ws + 2 * SZ_Q);              // conv2 out hi
    float* amx   = (float*)ws;                        // region [0,SZ_Q) free
    uint*  kAhi  = (uint*)(ws + (size_t)8 * 3 * PLANE * 4 + 4096);
    uint*  kAlo  = kAhi + 8 * 2048;
    uint*  kBhi  = kAlo + 8 * 2048;
    uint*  kBlo  = kBhi + 8 * 2048;

    // weight packs + g live in d_out (dead until final_mfma overwrites it)
    uint* wsp = (uint*)d_out;
    uint* wh1 = wsp;          uint* wl1 = wsp + 18432;
    uint* wh2 = wsp + 36864;  uint* wl2 = wsp + 55296;
    float* g  = (float*)(wsp + 73728);                // 512 floats in d_out

    wprep_kernel<<<dim3(72, 2), 256, 0, stream>>>(c1w, c2w, wh1, wl1, wh2, wl2);
    hipMemsetAsync(g, 0, 512 * sizeof(float), stream);

    dim3 cgrid(WW / 32, HH / 4, 8);  // (8, 64, 8)
    conv_mfma<1><<<cgrid, 256, 0, stream>>>(x, nullptr, wh1, wl1, c1b, pa, r1p,
                                            nullptr, nullptr);
    conv_mfma<2><<<cgrid, 256, 0, stream>>>(nullptr, r1p, wh2, wl2, c2b, nullptr,
                                            rph, amx, g);

    mlp_kernel<<<8, 256, 0, stream>>>(h, g, cw1, cb1, caa, cw2, cb2,
                                      fcw, fcb, k1w, k1b, k2w, k2b, k3w, k3b,
                                      kAhi, kAlo, kBhi, kBlo);
    final_mfma<<<dim3(PLANE / 64, 8), 256, 0, stream>>>(
        x, rph, amx, kAhi, kAlo, kBhi, kBlo, saw, sab, hcb, out);
}

// Round 21
// 550.818 us; speedup vs baseline: 2.3069x; 1.3078x over previous
//
#include <hip/hip_runtime.h>
#include <math.h>

#define HH 256
#define WW 256
#define CC 64
#define PLANE (HH*WW)

typedef short s16x8 __attribute__((ext_vector_type(8)));
typedef float f32x16 __attribute__((ext_vector_type(16)));
typedef unsigned int uint;
typedef uint u32x4v __attribute__((ext_vector_type(4)));

__device__ inline uint bf16rne(float f) {
    uint u = __float_as_uint(f);
    return (u + 0x7FFFu + ((u >> 16) & 1u)) >> 16;
}
__device__ inline float bf16val(uint h) { return __uint_as_float(h << 16); }
__device__ inline s16x8 fragpack(uint4 q) {
    u32x4v t = {q.x, q.y, q.z, q.w};
    return __builtin_bit_cast(s16x8, t);
}
// activation fragment-slot layout: dword (pix, dwi) at
//   (pix>>5)*1024 + (dwi>>2)*128 + (pix&31)*4 + (dwi&3)
__device__ inline size_t chunk_addr(int pix, int c2) {
    return (size_t)(pix >> 5) * 1024 + c2 * 128 + (pix & 31) * 4;
}
// weight fragment-slot layout: dword (tap, oc, dwi) at
//   tap*2048 + (dwi>>2)*256 + oc*4 + (dwi&3)   -> lane-dense dwordx4 loads

// ---------------- weight prep: split fp32 W into bf16 hi/lo ----------------
__global__ __launch_bounds__(256) void wprep_kernel(
    const float* __restrict__ w1, const float* __restrict__ w2,
    uint* __restrict__ wh1, uint* __restrict__ wl1,
    uint* __restrict__ wh2, uint* __restrict__ wl2)
{
    const int idx = blockIdx.x * 256 + threadIdx.x;      // 0..18431
    const float* w = blockIdx.y ? w2 : w1;
    uint* wh = blockIdx.y ? wh2 : wh1;
    uint* wl = blockIdx.y ? wl2 : wl1;
    const int tap = idx >> 11;           // 9
    const int oc  = (idx >> 5) & 63;     // 64
    const int icp = idx & 31;            // 32 ic-pairs (dword index)
    float w0 = w[(oc * 64 + 2 * icp) * 9 + tap];
    float w1v = w[(oc * 64 + 2 * icp + 1) * 9 + tap];
    uint h0 = bf16rne(w0); float l0 = w0 - bf16val(h0);
    uint h1 = bf16rne(w1v); float l1 = w1v - bf16val(h1);
    const int a = tap * 2048 + (icp >> 2) * 256 + oc * 4 + (icp & 3);
    wh[a] = h0 | (h1 << 16);
    wl[a] = bf16rne(l0) | (bf16rne(l1) << 16);
}

// ---------------- conv 3x3 reflect via MFMA, 4-row tile, LDS halo ----------
// wave w: Mtile mt = w&1 (32 oc), row-pair rq = w>>1 (rows rq*2, rq*2+1).
// MODE 1: input = fp32 NCHW x (fused repack, swizzle on ds_write).
//         PReLU + fragment-slot (hi) out.
// MODE 2: input = fragment-slot packed r1p (dense staged). hi out +
//         fused chan mean/max + fused gpool partials.
// Per tap: {8 ds_read_b128 + NEXT tap's 8 weight dwordx4} -> sched_barrier(0)
// -> 16 MFMA.
// launch_bounds (256,3) is the ONLY stable point: allocator lands at 80 VGPR,
// zero spill. (256,4) -> 64 VGPR + 270MB scratch; (256,6) -> acc spills, 1.3GB.
#define HPIX 204                 // 6*34 halo pixels
template<int MODE>
__global__ __launch_bounds__(256, 3) void conv_mfma(
    const float* __restrict__ xf,   // MODE 1: fp32 NCHW input
    const uint* __restrict__ xin,   // MODE 2: fragment-slot packed input
    const uint* __restrict__ wh, const uint* __restrict__ wl,
    const float* __restrict__ bias, const float* __restrict__ prelu,
    uint* __restrict__ op, float* __restrict__ amx, float* __restrict__ gsum)
{
    __shared__ uint lds[HPIX * 32];          // 26,112 B
    const int tid  = threadIdx.x;
    const int lane = tid & 63;
    const int wid  = tid >> 6;
    const int x0 = blockIdx.x * 32;
    const int y0 = blockIdx.y * 4;
    const int b  = blockIdx.z;
    const int colx = lane & 31;
    const int half = lane >> 5;
    const int mt = wid & 1;          // Mtile (oc group of 32)
    const int rq = wid >> 1;         // row pair: rows rq*2, rq*2+1

    // ---- stage halo
    if constexpr (MODE == 1) {
        // fused repack from fp32 NCHW: middle 32 cols
        const float* xb = xf + (size_t)b * CC * PLANE;
        const int cp = tid >> 3;       // channel pair 0..31
        const int q  = tid & 7;        // pixel quad 0..7
#pragma unroll
        for (int r = 0; r < 6; r++) {
            int gy = y0 - 1 + r; gy = gy < 0 ? 1 : (gy > 255 ? 254 : gy);
            const float* p0 = xb + (size_t)(2 * cp) * PLANE + gy * 256 + x0 + q * 4;
            const float4 a = *(const float4*)p0;
            const float4 c = *(const float4*)(p0 + PLANE);
            uint dd[4];
            dd[0] = bf16rne(a.x) | (bf16rne(c.x) << 16);
            dd[1] = bf16rne(a.y) | (bf16rne(c.y) << 16);
            dd[2] = bf16rne(a.z) | (bf16rne(c.z) << 16);
            dd[3] = bf16rne(a.w) | (bf16rne(c.w) << 16);
#pragma unroll
            for (int i = 0; i < 4; i++) {
                const int lpix = r * 34 + 1 + q * 4 + i;
                const int slot = (cp >> 2) ^ (lpix & 7);
                lds[(lpix * 8 + slot) * 4 + (cp & 3)] = dd[i];
            }
        }
        // edges: 6 rows x 2 cols x 32 cps
        if (tid < 192) {
            const int r = tid >> 5, cpe = tid & 31;
            int gy = y0 - 1 + r; gy = gy < 0 ? 1 : (gy > 255 ? 254 : gy);
#pragma unroll
            for (int e = 0; e < 2; e++) {
                int gx = e ? x0 + 32 : x0 - 1;
                gx = gx < 0 ? 1 : (gx > 255 ? 254 : gx);
                const float v0 = xb[(size_t)(2 * cpe) * PLANE + gy * 256 + gx];
                const float v1 = xb[(size_t)(2 * cpe + 1) * PLANE + gy * 256 + gx];
                const int lpix = r * 34 + (e ? 33 : 0);
                const int slot = (cpe >> 2) ^ (lpix & 7);
                lds[(lpix * 8 + slot) * 4 + (cpe & 3)] =
                    bf16rne(v0) | (bf16rne(v1) << 16);
            }
        }
    } else {
        // dense staged from fragment-slot packed input
        const uint* gb = xin + (size_t)b * PLANE * 32;
        uint4 st[6];
#pragma unroll
        for (int r = 0; r < 6; r++) {
            int gy = y0 - 1 + r; gy = gy < 0 ? 1 : (gy > 255 ? 254 : gy);
            st[r] = *(const uint4*)(gb + (size_t)(gy * 8 + (x0 >> 5)) * 1024 + tid * 4);
        }
        const int hcol = (tid & 31) + 1;
        const int c2s  = tid >> 5;
#pragma unroll
        for (int r = 0; r < 6; r++) {
            const int lpix = r * 34 + hcol;
            const int lslot = c2s ^ (lpix & 7);
            *(uint4*)&lds[(lpix * 8 + lslot) * 4] = st[r];
        }
        if (tid < 96) {
            const int r  = tid >> 4;
            const int e  = (tid >> 3) & 1;
            const int sl = tid & 7;
            int gy = y0 - 1 + r; gy = gy < 0 ? 1 : (gy > 255 ? 254 : gy);
            int gx = e ? x0 + 32 : x0 - 1;
            gx = gx < 0 ? 1 : (gx > 255 ? 254 : gx);
            const uint4 v = *(const uint4*)(gb + chunk_addr(gy * 256 + gx, sl));
            const int lpix = r * 34 + (e ? 33 : 0);
            const int lslot = sl ^ (lpix & 7);
            *(uint4*)&lds[(lpix * 8 + lslot) * 4] = v;
        }
    }

    // lane-dense weight base for this wave's Mtile; preload tap 0
    const uint* wbh = wh + half * 256 + (mt * 32 + colx) * 4;
    const uint* wbl = wl + half * 256 + (mt * 32 + colx) * 4;
    uint4 Hc[4], Lc[4];
#pragma unroll
    for (int c = 0; c < 4; c++) {
        Hc[c] = *(const uint4*)(wbh + c * 512);
        Lc[c] = *(const uint4*)(wbl + c * 512);
    }
    __syncthreads();

    f32x16 acc0 = (f32x16)0.f, acc1 = (f32x16)0.f;   // rows rq*2, rq*2+1

#pragma unroll
    for (int tap = 0; tap < 9; tap++) {
        const int dy = tap / 3, dx = tap % 3;
        const int pixb = (rq * 2 + dy) * 34 + dx + colx;   // row rq*2

        uint4 Ba[4], Bb[4];
#pragma unroll
        for (int c = 0; c < 4; c++) {
            const int c2 = c * 2 + half;
            const int p0 = pixb, p1 = pixb + 34;
            Ba[c] = *(const uint4*)&lds[(p0 * 8 + (c2 ^ (p0 & 7))) * 4];
            Bb[c] = *(const uint4*)&lds[(p1 * 8 + (c2 ^ (p1 & 7))) * 4];
        }
        uint4 Hn[4], Ln[4];
        if (tap < 8) {
#pragma unroll
            for (int c = 0; c < 4; c++) {
                Hn[c] = *(const uint4*)(wbh + (tap + 1) * 2048 + c * 512);
                Ln[c] = *(const uint4*)(wbl + (tap + 1) * 2048 + c * 512);
            }
        }
        __builtin_amdgcn_sched_barrier(0);
#pragma unroll
        for (int c = 0; c < 4; c++) {
            const s16x8 b0 = fragpack(Ba[c]), b1 = fragpack(Bb[c]);
            const s16x8 ah = fragpack(Hc[c]), al = fragpack(Lc[c]);
            acc0 = __builtin_amdgcn_mfma_f32_32x32x16_bf16(ah, b0, acc0, 0, 0, 0);
            acc1 = __builtin_amdgcn_mfma_f32_32x32x16_bf16(ah, b1, acc1, 0, 0, 0);
            acc0 = __builtin_amdgcn_mfma_f32_32x32x16_bf16(al, b0, acc0, 0, 0, 0);
            acc1 = __builtin_amdgcn_mfma_f32_32x32x16_bf16(al, b1, acc1, 0, 0, 0);
        }
        if (tap < 8) {
#pragma unroll
            for (int c = 0; c < 4; c++) { Hc[c] = Hn[c]; Lc[c] = Ln[c]; }
        }
    }

    // ---- epilogue. C/D layout (32x32): col=lane&31 (pixel), row=(j&3)+8*(j>>2)+4*half (oc)
    const int pcol = colx, seg = half;
    const int pixg = (y0 + wid) * 256 + x0 + pcol;
    __syncthreads();                    // halo reads done; reuse lds for transpose
#define STH(ACC, RR, DOPRELU) { \
    _Pragma("unroll") \
    for (int j = 0; j < 16; j += 2) { \
        const int row = (j & 3) + 8 * (j >> 2) + 4 * half; \
        const int oc = mt * 32 + row; \
        float v0 = ACC[j]     + bias[oc]; \
        float v1 = ACC[j + 1] + bias[oc + 1]; \
        if (DOPRELU) { \
            const float a0 = prelu[oc], a1 = prelu[oc + 1]; \
            v0 = fmaxf(v0, 0.f) + a0 * fminf(v0, 0.f); \
            v1 = fmaxf(v1, 0.f) + a1 * fminf(v1, 0.f); \
        } \
        const int icp = oc >> 1; \
        lds[((RR) * 32 + icp) * 32 + (colx ^ icp)] = \
            bf16rne(v0) | (bf16rne(v1) << 16); \
    } }
    STH(acc0, rq * 2, (MODE == 1)) STH(acc1, rq * 2 + 1, (MODE == 1))
#undef STH
    __syncthreads();
    uint d[16];
#pragma unroll
    for (int i = 0; i < 16; i++) {
        const int icp = seg * 16 + i;
        d[i] = lds[(wid * 32 + icp) * 32 + (pcol ^ icp)];
    }
    uint* o = op + (size_t)b * PLANE * 32 + chunk_addr(pixg, seg * 4);
#pragma unroll
    for (int k = 0; k < 4; k++)
        *(uint4*)(o + k * 128) = make_uint4(d[4*k], d[4*k+1], d[4*k+2], d[4*k+3]);

    if constexpr (MODE == 2) {
        float s_ = 0.f, m_ = -INFINITY;
#pragma unroll
        for (int i = 0; i < 16; i++) {
            float ve = bf16val(d[i] & 0xffffu);
            float vo = bf16val(d[i] >> 16);
            s_ += ve + vo;
            m_ = fmaxf(m_, fmaxf(ve, vo));
        }
        const int cp_g = tid & 31;
        const int hr_g = tid >> 5;
        const int row_g = hr_g >> 1;
        const int pc0_g = (hr_g & 1) * 16;
        float gs0 = 0.f, gs1 = 0.f;
#pragma unroll
        for (int p = 0; p < 16; p++) {
            const int pc = pc0_g + p;
            const uint v = lds[(row_g * 32 + cp_g) * 32 + (pc ^ cp_g)];
            gs0 += bf16val(v & 0xffffu);
            gs1 += bf16val(v >> 16);
        }
        s_ += __shfl_xor(s_, 32, 64);
        m_ = fmaxf(m_, __shfl_xor(m_, 32, 64));
        if (seg == 0) {
            amx[(size_t)b * 2 * PLANE + pixg] = s_ * (1.f / 64.f);
            amx[(size_t)b * 2 * PLANE + PLANE + pixg] = m_;
        }
        __syncthreads();
        lds[4096 + hr_g * 64 + 2 * cp_g]     = __float_as_uint(gs0);
        lds[4096 + hr_g * 64 + 2 * cp_g + 1] = __float_as_uint(gs1);
        __syncthreads();
        if (tid < 64) {
            float t = 0.f;
#pragma unroll
            for (int h8 = 0; h8 < 8; h8++)
                t += __uint_as_float(lds[4096 + h8 * 64 + tid]);
            atomicAdd(&gsum[b * 64 + tid], t * (1.f / PLANE));
        }
    }
}

// ---------------- tiny MLPs -> hyper kernels, fragment-slot hi/lo --------
__global__ __launch_bounds__(256) void mlp_kernel(
    const float* __restrict__ h, const float* __restrict__ g,
    const float* __restrict__ ca_w1, const float* __restrict__ ca_b1,
    const float* __restrict__ ca_a,
    const float* __restrict__ ca_w2, const float* __restrict__ ca_b2,
    const float* __restrict__ fc_w, const float* __restrict__ fc_b,
    const float* __restrict__ k1_w, const float* __restrict__ k1_b,
    const float* __restrict__ k2_w, const float* __restrict__ k2_b,
    const float* __restrict__ k3_w, const float* __restrict__ k3_b,
    uint* __restrict__ kAhi, uint* __restrict__ kAlo,
    uint* __restrict__ kBhi, uint* __restrict__ kBlo)
{
    int b = blockIdx.x, tid = threadIdx.x;
    __shared__ float gb[64], t16[16], u32[32], v32[32], cg1[32], casig[64];

    if (tid < 64) gb[tid] = g[b * 64 + tid];
    __syncthreads();

    if (tid < 16) {
        float s = fc_b[tid];
        for (int j = 0; j < 16; j++) s += fc_w[tid * 16 + j] * h[b * 16 + j];
        t16[tid] = s >= 0.f ? s : 0.01f * s;
    }
    if (tid < 32) {
        float c1 = ca_b1[tid];
        for (int j = 0; j < 64; j++) c1 += ca_w1[tid * 64 + j] * gb[j];
        cg1[tid] = fmaxf(c1, 0.f) + ca_a[tid] * fminf(c1, 0.f);
    }
    __syncthreads();
    if (tid < 32) {
        float s = k1_b[tid];
        for (int j = 0; j < 16; j++) s += k1_w[tid * 16 + j] * t16[j];
        u32[tid] = s >= 0.f ? s : 0.01f * s;
    }
    if (tid < 64) {
        float c2 = ca_b2[tid];
        for (int j = 0; j < 32; j++) c2 += ca_w2[tid * 32 + j] * cg1[j];
        casig[tid] = 1.f / (1.f + expf(-c2));
    }
    __syncthreads();
    if (tid < 32) {
        float s = k2_b[tid];
        for (int j = 0; j < 32; j++) s += k2_w[tid * 32 + j] * u32[j];
        v32[tid] = s >= 0.f ? s : 0.01f * s;
    }
    __syncthreads();
    // k3: 8192 outputs, adjacent pairs -> one packed dword, fragment-slot store
    for (int o2 = tid; o2 < 4096; o2 += 256) {
        const int o = o2 * 2;
        const int oc = o >> 7;        // /128
        const int i = o & 127;        // even
        float s0 = k3_b[o], s1 = k3_b[o + 1];
        for (int j = 0; j < 32; j++) {
            s0 += k3_w[(size_t)o * 32 + j] * v32[j];
            s1 += k3_w[(size_t)(o + 1) * 32 + j] * v32[j];
        }
        uint *hi, *lo;
        if (i < 64) { hi = kAhi; lo = kAlo; }
        else { s0 *= casig[i - 64]; s1 *= casig[i - 63]; hi = kBhi; lo = kBlo; }
        const int cp = (i & 63) >> 1;
        uint h0 = bf16rne(s0); float l0 = s0 - bf16val(h0);
        uint h1 = bf16rne(s1); float l1 = s1 - bf16val(h1);
        const size_t a = (size_t)b * 2048 + (cp >> 2) * 256 + oc * 4 + (cp & 3);
        hi[a] = h0 | (h1 << 16);
        lo[a] = bf16rne(l0) | (bf16rne(l1) << 16);
    }
}

// ---------------- final via MFMA + inlined spatial-attention conv -----------
// out = x + hcb + sig(sa3x3(amx))*(A.r) + (B.r);  r = hi only
__global__ __launch_bounds__(256, 8) void final_mfma(
    const float* __restrict__ x, const uint* __restrict__ rph,
    const float* __restrict__ amx,
    const uint* __restrict__ kAhi, const uint* __restrict__ kAlo,
    const uint* __restrict__ kBhi, const uint* __restrict__ kBlo,
    const float* __restrict__ sa_w, const float* __restrict__ sa_b,
    const float* __restrict__ hcb, float* __restrict__ out)
{
    const int tid = threadIdx.x;
    const int lane = tid & 63;
    const int wid = tid >> 6;
    const int mt = wid & 1;          // oc Mtile
    const int gq = wid >> 1;         // pixel group
    const int b = blockIdx.y;
    const int colx = lane & 31;
    const int half = lane >> 5;
    const int pix = blockIdx.x * 64 + gq * 32 + colx;
    const int pgroup = blockIdx.x * 2 + gq;   // pix >> 5

    const size_t kb = (size_t)b * 2048 + half * 256 + (size_t)(mt * 32 + colx) * 4;
    uint4 KAh[4], KAl[4], KBh[4], KBl[4];
#pragma unroll
    for (int c = 0; c < 4; c++) {
        KAh[c] = *(const uint4*)(kAhi + kb + c * 512);
        KAl[c] = *(const uint4*)(kAlo + kb + c * 512);
        KBh[c] = *(const uint4*)(kBhi + kb + c * 512);
        KBl[c] = *(const uint4*)(kBlo + kb + c * 512);
    }
    const size_t rb = (size_t)b * PLANE * 32 + (size_t)pgroup * 1024
                    + half * 128 + colx * 4;
    uint4 Bh[4];
#pragma unroll
    for (int c = 0; c < 4; c++)
        Bh[c] = *(const uint4*)(rph + rb + c * 256);

    const int xx = pix & 255, yy = pix >> 8;
    float sacc = sa_b[0];
    const float* ab = amx + (size_t)b * 2 * PLANE;
#pragma unroll
    for (int cc = 0; cc < 2; cc++)
#pragma unroll
        for (int dy2 = -1; dy2 <= 1; dy2++)
#pragma unroll
            for (int dx2 = -1; dx2 <= 1; dx2++) {
                int gx = xx + dx2; gx = gx < 0 ? 1 : (gx >= WW ? 2 * WW - 2 - gx : gx);
                int gy = yy + dy2; gy = gy < 0 ? 1 : (gy >= HH ? 2 * HH - 2 - gy : gy);
                sacc += sa_w[cc * 9 + (dy2 + 1) * 3 + (dx2 + 1)]
                      * ab[(size_t)cc * PLANE + gy * WW + gx];
            }
    const float sig = 1.f / (1.f + expf(-sacc));

    f32x16 accA = (f32x16)0.f, accB = (f32x16)0.f;
#pragma unroll
    for (int c = 0; c < 4; c++) {
        const s16x8 bh = fragpack(Bh[c]);
        const s16x8 ah = fragpack(KAh[c]), al = fragpack(KAl[c]);
        const s16x8 ch = fragpack(KBh[c]), cl = fragpack(KBl[c]);
        accA = __builtin_amdgcn_mfma_f32_32x32x16_bf16(ah, bh, accA, 0, 0, 0);
        accA = __builtin_amdgcn_mfma_f32_32x32x16_bf16(al, bh, accA, 0, 0, 0);
        accB = __builtin_amdgcn_mfma_f32_32x32x16_bf16(ch, bh, accB, 0, 0, 0);
        accB = __builtin_amdgcn_mfma_f32_32x32x16_bf16(cl, bh, accB, 0, 0, 0);
    }
#pragma unroll
    for (int j = 0; j < 16; j++) {
        const int row = (j & 3) + 8 * (j >> 2) + 4 * half;
        const int oc = mt * 32 + row;
        const size_t idx = ((size_t)b * 64 + oc) * PLANE + pix;
        out[idx] = x[idx] + hcb[oc] + sig * accA[j] + accB[j];
    }
}

extern "C" void kernel_launch(void* const* d_in, const int* in_sizes, int n_in,
                              void* d_out, int out_size, void* d_ws, size_t ws_size,
                              hipStream_t stream) {
    const float* x   = (const float*)d_in[0];
    const float* h   = (const float*)d_in[1];
    const float* c1w = (const float*)d_in[2];
    const float* c1b = (const float*)d_in[3];
    const float* pa  = (const float*)d_in[4];
    const float* c2w = (const float*)d_in[5];
    const float* c2b = (const float*)d_in[6];
    const float* saw = (const float*)d_in[7];
    const float* sab = (const float*)d_in[8];
    const float* cw1 = (const float*)d_in[9];
    const float* cb1 = (const float*)d_in[10];
    const float* caa = (const float*)d_in[11];
    const float* cw2 = (const float*)d_in[12];
    const float* cb2 = (const float*)d_in[13];
    const float* fcw = (const float*)d_in[14];
    const float* fcb = (const float*)d_in[15];
    const float* k1w = (const float*)d_in[16];
    const float* k1b = (const float*)d_in[17];
    const float* k2w = (const float*)d_in[18];
    const float* k2b = (const float*)d_in[19];
    const float* k3w = (const float*)d_in[20];
    const float* k3b = (const float*)d_in[21];
    const float* hcb = (const float*)d_in[22];
    float* out = (float*)d_out;

    char* ws = (char*)d_ws;
    const size_t SZ_Q = (size_t)8 * PLANE * 32 * 4;   // 67,108,864 (packed)
    uint*  r1p = (uint*)(ws + SZ_Q);                  // conv1 out (hi)
    uint*  rph = (uint*)(ws + 2 * SZ_Q);              // conv2 out hi
    float* amx   = (float*)ws;                        // region [0,SZ_Q) free
    uint*  kAhi  = (uint*)(ws + (size_t)8 * 3 * PLANE * 4 + 4096);
    uint*  kAlo  = kAhi + 8 * 2048;
    uint*  kBhi  = kAlo + 8 * 2048;
    uint*  kBlo  = kBhi + 8 * 2048;

    // weight packs + g live in d_out (dead until final_mfma overwrites it)
    uint* wsp = (uint*)d_out;
    uint* wh1 = wsp;          uint* wl1 = wsp + 18432;
    uint* wh2 = wsp + 36864;  uint* wl2 = wsp + 55296;
    float* g  = (float*)(wsp + 73728);                // 512 floats in d_out

    wprep_kernel<<<dim3(72, 2), 256, 0, stream>>>(c1w, c2w, wh1, wl1, wh2, wl2);
    hipMemsetAsync(g, 0, 512 * sizeof(float), stream);

    dim3 cgrid(WW / 32, HH / 4, 8);  // (8, 64, 8)
    conv_mfma<1><<<cgrid, 256, 0, stream>>>(x, nullptr, wh1, wl1, c1b, pa, r1p,
                                            nullptr, nullptr);
    conv_mfma<2><<<cgrid, 256, 0, stream>>>(nullptr, r1p, wh2, wl2, c2b, nullptr,
                                            rph, amx, g);

    mlp_kernel<<<8, 256, 0, stream>>>(h, g, cw1, cb1, caa, cw2, cb2,
                                      fcw, fcb, k1w, k1b, k2w, k2b, k3w, k3b,
                                      kAhi, kAlo, kBhi, kBlo);
    final_mfma<<<dim3(PLANE / 64, 8), 256, 0, stream>>>(
        x, rph, amx, kAhi, kAlo, kBhi, kBlo, saw, sab, hcb, out);
}

// Round 22
// 515.112 us; speedup vs baseline: 2.4668x; 1.0693x over previous
//
#include <hip/hip_runtime.h>
#include <math.h>

#define HH 256
#define WW 256
#define CC 64
#define PLANE (HH*WW)

typedef short s16x8 __attribute__((ext_vector_type(8)));
typedef float f32x16 __attribute__((ext_vector_type(16)));
typedef unsigned int uint;
typedef uint u32x4v __attribute__((ext_vector_type(4)));

__device__ inline uint bf16rne(float f) {
    uint u = __float_as_uint(f);
    return (u + 0x7FFFu + ((u >> 16) & 1u)) >> 16;
}
__device__ inline float bf16val(uint h) { return __uint_as_float(h << 16); }
__device__ inline s16x8 fragpack(uint4 q) {
    u32x4v t = {q.x, q.y, q.z, q.w};
    return __builtin_bit_cast(s16x8, t);
}
// activation fragment-slot layout: dword (pix, dwi) at
//   (pix>>5)*1024 + (dwi>>2)*128 + (pix&31)*4 + (dwi&3)
__device__ inline size_t chunk_addr(int pix, int c2) {
    return (size_t)(pix >> 5) * 1024 + c2 * 128 + (pix & 31) * 4;
}
// weight fragment-slot layout: dword (tap, oc, dwi) at
//   tap*2048 + (dwi>>2)*256 + oc*4 + (dwi&3)   -> lane-dense dwordx4 loads

// ---------------- weight prep: split fp32 W into bf16 hi/lo ----------------
__global__ __launch_bounds__(256) void wprep_kernel(
    const float* __restrict__ w1, const float* __restrict__ w2,
    uint* __restrict__ wh1, uint* __restrict__ wl1,
    uint* __restrict__ wh2, uint* __restrict__ wl2)
{
    const int idx = blockIdx.x * 256 + threadIdx.x;      // 0..18431
    const float* w = blockIdx.y ? w2 : w1;
    uint* wh = blockIdx.y ? wh2 : wh1;
    uint* wl = blockIdx.y ? wl2 : wl1;
    const int tap = idx >> 11;           // 9
    const int oc  = (idx >> 5) & 63;     // 64
    const int icp = idx & 31;            // 32 ic-pairs (dword index)
    float w0 = w[(oc * 64 + 2 * icp) * 9 + tap];
    float w1v = w[(oc * 64 + 2 * icp + 1) * 9 + tap];
    uint h0 = bf16rne(w0); float l0 = w0 - bf16val(h0);
    uint h1 = bf16rne(w1v); float l1 = w1v - bf16val(h1);
    const int a = tap * 2048 + (icp >> 2) * 256 + oc * 4 + (icp & 3);
    wh[a] = h0 | (h1 << 16);
    wl[a] = bf16rne(l0) | (bf16rne(l1) << 16);
}

// ---------------- conv 3x3 reflect via MFMA, 4-row tile, LDS halo ----------
// wave w: Mtile mt = w&1 (32 oc), row-pair rq = w>>1 (rows rq*2, rq*2+1).
// MODE 1: input = fp32 NCHW x (fused repack, swizzle on ds_write).
//         PReLU + fragment-slot (hi) out.
// MODE 2: input = fragment-slot packed r1p (dense staged). hi out +
//         fused chan mean/max + fused gpool partials.
// Per tap: {8 ds_read_b128 + NEXT tap's 8 weight dwordx4} -> sched_barrier(0)
// -> 16 MFMA.
// launch_bounds (256,3) is the ONLY stable point: allocator lands at 80 VGPR,
// zero spill. (256,4) -> 64 VGPR + 270MB scratch; (256,6) -> acc spills, 1.3GB.
#define HPIX 204                 // 6*34 halo pixels
template<int MODE>
__global__ __launch_bounds__(256, 3) void conv_mfma(
    const float* __restrict__ xf,   // MODE 1: fp32 NCHW input
    const uint* __restrict__ xin,   // MODE 2: fragment-slot packed input
    const uint* __restrict__ wh, const uint* __restrict__ wl,
    const float* __restrict__ bias, const float* __restrict__ prelu,
    uint* __restrict__ op, float* __restrict__ amx, float* __restrict__ gsum)
{
    __shared__ uint lds[HPIX * 32];          // 26,112 B
    const int tid  = threadIdx.x;
    const int lane = tid & 63;
    const int wid  = tid >> 6;
    const int x0 = blockIdx.x * 32;
    const int y0 = blockIdx.y * 4;
    const int b  = blockIdx.z;
    const int colx = lane & 31;
    const int half = lane >> 5;
    const int mt = wid & 1;          // Mtile (oc group of 32)
    const int rq = wid >> 1;         // row pair: rows rq*2, rq*2+1

    // ---- stage halo
    if constexpr (MODE == 1) {
        // fused repack from fp32 NCHW: middle 32 cols
        const float* xb = xf + (size_t)b * CC * PLANE;
        const int cp = tid >> 3;       // channel pair 0..31
        const int q  = tid & 7;        // pixel quad 0..7
#pragma unroll
        for (int r = 0; r < 6; r++) {
            int gy = y0 - 1 + r; gy = gy < 0 ? 1 : (gy > 255 ? 254 : gy);
            const float* p0 = xb + (size_t)(2 * cp) * PLANE + gy * 256 + x0 + q * 4;
            const float4 a = *(const float4*)p0;
            const float4 c = *(const float4*)(p0 + PLANE);
            uint dd[4];
            dd[0] = bf16rne(a.x) | (bf16rne(c.x) << 16);
            dd[1] = bf16rne(a.y) | (bf16rne(c.y) << 16);
            dd[2] = bf16rne(a.z) | (bf16rne(c.z) << 16);
            dd[3] = bf16rne(a.w) | (bf16rne(c.w) << 16);
#pragma unroll
            for (int i = 0; i < 4; i++) {
                const int lpix = r * 34 + 1 + q * 4 + i;
                const int slot = (cp >> 2) ^ (lpix & 7);
                lds[(lpix * 8 + slot) * 4 + (cp & 3)] = dd[i];
            }
        }
        // edges: 6 rows x 2 cols x 32 cps
        if (tid < 192) {
            const int r = tid >> 5, cpe = tid & 31;
            int gy = y0 - 1 + r; gy = gy < 0 ? 1 : (gy > 255 ? 254 : gy);
#pragma unroll
            for (int e = 0; e < 2; e++) {
                int gx = e ? x0 + 32 : x0 - 1;
                gx = gx < 0 ? 1 : (gx > 255 ? 254 : gx);
                const float v0 = xb[(size_t)(2 * cpe) * PLANE + gy * 256 + gx];
                const float v1 = xb[(size_t)(2 * cpe + 1) * PLANE + gy * 256 + gx];
                const int lpix = r * 34 + (e ? 33 : 0);
                const int slot = (cpe >> 2) ^ (lpix & 7);
                lds[(lpix * 8 + slot) * 4 + (cpe & 3)] =
                    bf16rne(v0) | (bf16rne(v1) << 16);
            }
        }
    } else {
        // dense staged from fragment-slot packed input
        const uint* gb = xin + (size_t)b * PLANE * 32;
        uint4 st[6];
#pragma unroll
        for (int r = 0; r < 6; r++) {
            int gy = y0 - 1 + r; gy = gy < 0 ? 1 : (gy > 255 ? 254 : gy);
            st[r] = *(const uint4*)(gb + (size_t)(gy * 8 + (x0 >> 5)) * 1024 + tid * 4);
        }
        const int hcol = (tid & 31) + 1;
        const int c2s  = tid >> 5;
#pragma unroll
        for (int r = 0; r < 6; r++) {
            const int lpix = r * 34 + hcol;
            const int lslot = c2s ^ (lpix & 7);
            *(uint4*)&lds[(lpix * 8 + lslot) * 4] = st[r];
        }
        if (tid < 96) {
            const int r  = tid >> 4;
            const int e  = (tid >> 3) & 1;
            const int sl = tid & 7;
            int gy = y0 - 1 + r; gy = gy < 0 ? 1 : (gy > 255 ? 254 : gy);
            int gx = e ? x0 + 32 : x0 - 1;
            gx = gx < 0 ? 1 : (gx > 255 ? 254 : gx);
            const uint4 v = *(const uint4*)(gb + chunk_addr(gy * 256 + gx, sl));
            const int lpix = r * 34 + (e ? 33 : 0);
            const int lslot = sl ^ (lpix & 7);
            *(uint4*)&lds[(lpix * 8 + lslot) * 4] = v;
        }
    }

    // lane-dense weight base for this wave's Mtile; preload tap 0
    const uint* wbh = wh + half * 256 + (mt * 32 + colx) * 4;
    const uint* wbl = wl + half * 256 + (mt * 32 + colx) * 4;
    uint4 Hc[4], Lc[4];
#pragma unroll
    for (int c = 0; c < 4; c++) {
        Hc[c] = *(const uint4*)(wbh + c * 512);
        Lc[c] = *(const uint4*)(wbl + c * 512);
    }
    __syncthreads();

    f32x16 acc0 = (f32x16)0.f, acc1 = (f32x16)0.f;   // rows rq*2, rq*2+1

#pragma unroll
    for (int tap = 0; tap < 9; tap++) {
        const int dy = tap / 3, dx = tap % 3;
        const int pixb = (rq * 2 + dy) * 34 + dx + colx;   // row rq*2

        uint4 Ba[4], Bb[4];
#pragma unroll
        for (int c = 0; c < 4; c++) {
            const int c2 = c * 2 + half;
            const int p0 = pixb, p1 = pixb + 34;
            Ba[c] = *(const uint4*)&lds[(p0 * 8 + (c2 ^ (p0 & 7))) * 4];
            Bb[c] = *(const uint4*)&lds[(p1 * 8 + (c2 ^ (p1 & 7))) * 4];
        }
        uint4 Hn[4], Ln[4];
        if (tap < 8) {
#pragma unroll
            for (int c = 0; c < 4; c++) {
                Hn[c] = *(const uint4*)(wbh + (tap + 1) * 2048 + c * 512);
                Ln[c] = *(const uint4*)(wbl + (tap + 1) * 2048 + c * 512);
            }
        }
        __builtin_amdgcn_sched_barrier(0);
#pragma unroll
        for (int c = 0; c < 4; c++) {
            const s16x8 b0 = fragpack(Ba[c]), b1 = fragpack(Bb[c]);
            const s16x8 ah = fragpack(Hc[c]), al = fragpack(Lc[c]);
            acc0 = __builtin_amdgcn_mfma_f32_32x32x16_bf16(ah, b0, acc0, 0, 0, 0);
            acc1 = __builtin_amdgcn_mfma_f32_32x32x16_bf16(ah, b1, acc1, 0, 0, 0);
            acc0 = __builtin_amdgcn_mfma_f32_32x32x16_bf16(al, b0, acc0, 0, 0, 0);
            acc1 = __builtin_amdgcn_mfma_f32_32x32x16_bf16(al, b1, acc1, 0, 0, 0);
        }
        if (tap < 8) {
#pragma unroll
            for (int c = 0; c < 4; c++) { Hc[c] = Hn[c]; Lc[c] = Ln[c]; }
        }
    }

    // ---- epilogue. C/D layout (32x32): col=lane&31 (pixel), row=(j&3)+8*(j>>2)+4*half (oc)
    const int pcol = colx, seg = half;
    const int pixg = (y0 + wid) * 256 + x0 + pcol;
    __syncthreads();                    // halo reads done; reuse lds for transpose
#define STH(ACC, RR, DOPRELU) { \
    _Pragma("unroll") \
    for (int j = 0; j < 16; j += 2) { \
        const int row = (j & 3) + 8 * (j >> 2) + 4 * half; \
        const int oc = mt * 32 + row; \
        float v0 = ACC[j]     + bias[oc]; \
        float v1 = ACC[j + 1] + bias[oc + 1]; \
        if (DOPRELU) { \
            const float a0 = prelu[oc], a1 = prelu[oc + 1]; \
            v0 = fmaxf(v0, 0.f) + a0 * fminf(v0, 0.f); \
            v1 = fmaxf(v1, 0.f) + a1 * fminf(v1, 0.f); \
        } \
        const int icp = oc >> 1; \
        lds[((RR) * 32 + icp) * 32 + (colx ^ icp)] = \
            bf16rne(v0) | (bf16rne(v1) << 16); \
    } }
    STH(acc0, rq * 2, (MODE == 1)) STH(acc1, rq * 2 + 1, (MODE == 1))
#undef STH
    __syncthreads();
    uint d[16];
#pragma unroll
    for (int i = 0; i < 16; i++) {
        const int icp = seg * 16 + i;
        d[i] = lds[(wid * 32 + icp) * 32 + (pcol ^ icp)];
    }
    uint* o = op + (size_t)b * PLANE * 32 + chunk_addr(pixg, seg * 4);
#pragma unroll
    for (int k = 0; k < 4; k++)
        *(uint4*)(o + k * 128) = make_uint4(d[4*k], d[4*k+1], d[4*k+2], d[4*k+3]);

    if constexpr (MODE == 2) {
        float s_ = 0.f, m_ = -INFINITY;
#pragma unroll
        for (int i = 0; i < 16; i++) {
            float ve = bf16val(d[i] & 0xffffu);
            float vo = bf16val(d[i] >> 16);
            s_ += ve + vo;
            m_ = fmaxf(m_, fmaxf(ve, vo));
        }
        const int cp_g = tid & 31;
        const int hr_g = tid >> 5;
        const int row_g = hr_g >> 1;
        const int pc0_g = (hr_g & 1) * 16;
        float gs0 = 0.f, gs1 = 0.f;
#pragma unroll
        for (int p = 0; p < 16; p++) {
            const int pc = pc0_g + p;
            const uint v = lds[(row_g * 32 + cp_g) * 32 + (pc ^ cp_g)];
            gs0 += bf16val(v & 0xffffu);
            gs1 += bf16val(v >> 16);
        }
        s_ += __shfl_xor(s_, 32, 64);
        m_ = fmaxf(m_, __shfl_xor(m_, 32, 64));
        if (seg == 0) {
            amx[(size_t)b * 2 * PLANE + pixg] = s_ * (1.f / 64.f);
            amx[(size_t)b * 2 * PLANE + PLANE + pixg] = m_;
        }
        __syncthreads();
        lds[4096 + hr_g * 64 + 2 * cp_g]     = __float_as_uint(gs0);
        lds[4096 + hr_g * 64 + 2 * cp_g + 1] = __float_as_uint(gs1);
        __syncthreads();
        if (tid < 64) {
            float t = 0.f;
#pragma unroll
            for (int h8 = 0; h8 < 8; h8++)
                t += __uint_as_float(lds[4096 + h8 * 64 + tid]);
            atomicAdd(&gsum[b * 64 + tid], t * (1.f / PLANE));
        }
    }
}

// ---------------- tiny MLPs -> hyper kernels, fragment-slot hi/lo --------
// grid (8, 16): every block redundantly computes the tiny chain (fc/k1/k2/ca,
// deterministic), then handles a disjoint 256-output slice of k3 ->
// 1 iteration/thread instead of 16 and 128 blocks instead of 8.
__global__ __launch_bounds__(256) void mlp_kernel(
    const float* __restrict__ h, const float* __restrict__ g,
    const float* __restrict__ ca_w1, const float* __restrict__ ca_b1,
    const float* __restrict__ ca_a,
    const float* __restrict__ ca_w2, const float* __restrict__ ca_b2,
    const float* __restrict__ fc_w, const float* __restrict__ fc_b,
    const float* __restrict__ k1_w, const float* __restrict__ k1_b,
    const float* __restrict__ k2_w, const float* __restrict__ k2_b,
    const float* __restrict__ k3_w, const float* __restrict__ k3_b,
    uint* __restrict__ kAhi, uint* __restrict__ kAlo,
    uint* __restrict__ kBhi, uint* __restrict__ kBlo)
{
    int b = blockIdx.x, tid = threadIdx.x;
    __shared__ float gb[64], t16[16], u32[32], v32[32], cg1[32], casig[64];

    if (tid < 64) gb[tid] = g[b * 64 + tid];
    __syncthreads();

    if (tid < 16) {
        float s = fc_b[tid];
        for (int j = 0; j < 16; j++) s += fc_w[tid * 16 + j] * h[b * 16 + j];
        t16[tid] = s >= 0.f ? s : 0.01f * s;
    }
    if (tid < 32) {
        float c1 = ca_b1[tid];
        for (int j = 0; j < 64; j++) c1 += ca_w1[tid * 64 + j] * gb[j];
        cg1[tid] = fmaxf(c1, 0.f) + ca_a[tid] * fminf(c1, 0.f);
    }
    __syncthreads();
    if (tid < 32) {
        float s = k1_b[tid];
        for (int j = 0; j < 16; j++) s += k1_w[tid * 16 + j] * t16[j];
        u32[tid] = s >= 0.f ? s : 0.01f * s;
    }
    if (tid < 64) {
        float c2 = ca_b2[tid];
        for (int j = 0; j < 32; j++) c2 += ca_w2[tid * 32 + j] * cg1[j];
        casig[tid] = 1.f / (1.f + expf(-c2));
    }
    __syncthreads();
    if (tid < 32) {
        float s = k2_b[tid];
        for (int j = 0; j < 32; j++) s += k2_w[tid * 32 + j] * u32[j];
        v32[tid] = s >= 0.f ? s : 0.01f * s;
    }
    __syncthreads();
    // k3: this block's 256-output slice; adjacent pairs -> one packed dword
    {
        const int o2 = blockIdx.y * 256 + tid;    // 0..4095
        const int o = o2 * 2;
        const int oc = o >> 7;        // /128
        const int i = o & 127;        // even
        float s0 = k3_b[o], s1 = k3_b[o + 1];
        for (int j = 0; j < 32; j++) {
            s0 += k3_w[(size_t)o * 32 + j] * v32[j];
            s1 += k3_w[(size_t)(o + 1) * 32 + j] * v32[j];
        }
        uint *hi, *lo;
        if (i < 64) { hi = kAhi; lo = kAlo; }
        else { s0 *= casig[i - 64]; s1 *= casig[i - 63]; hi = kBhi; lo = kBlo; }
        const int cp = (i & 63) >> 1;
        uint h0 = bf16rne(s0); float l0 = s0 - bf16val(h0);
        uint h1 = bf16rne(s1); float l1 = s1 - bf16val(h1);
        const size_t a = (size_t)b * 2048 + (cp >> 2) * 256 + oc * 4 + (cp & 3);
        hi[a] = h0 | (h1 << 16);
        lo[a] = bf16rne(l0) | (bf16rne(l1) << 16);
    }
}

// ---------------- final via MFMA + inlined spatial-attention conv -----------
// out = x + hcb + sig(sa3x3(amx))*(A.r) + (B.r);  r = hi only
__global__ __launch_bounds__(256, 8) void final_mfma(
    const float* __restrict__ x, const uint* __restrict__ rph,
    const float* __restrict__ amx,
    const uint* __restrict__ kAhi, const uint* __restrict__ kAlo,
    const uint* __restrict__ kBhi, const uint* __restrict__ kBlo,
    const float* __restrict__ sa_w, const float* __restrict__ sa_b,
    const float* __restrict__ hcb, float* __restrict__ out)
{
    const int tid = threadIdx.x;
    const int lane = tid & 63;
    const int wid = tid >> 6;
    const int mt = wid & 1;          // oc Mtile
    const int gq = wid >> 1;         // pixel group
    const int b = blockIdx.y;
    const int colx = lane & 31;
    const int half = lane >> 5;
    const int pix = blockIdx.x * 64 + gq * 32 + colx;
    const int pgroup = blockIdx.x * 2 + gq;   // pix >> 5

    const size_t kb = (size_t)b * 2048 + half * 256 + (size_t)(mt * 32 + colx) * 4;
    uint4 KAh[4], KAl[4], KBh[4], KBl[4];
#pragma unroll
    for (int c = 0; c < 4; c++) {
        KAh[c] = *(const uint4*)(kAhi + kb + c * 512);
        KAl[c] = *(const uint4*)(kAlo + kb + c * 512);
        KBh[c] = *(const uint4*)(kBhi + kb + c * 512);
        KBl[c] = *(const uint4*)(kBlo + kb + c * 512);
    }
    const size_t rb = (size_t)b * PLANE * 32 + (size_t)pgroup * 1024
                    + half * 128 + colx * 4;
    uint4 Bh[4];
#pragma unroll
    for (int c = 0; c < 4; c++)
        Bh[c] = *(const uint4*)(rph + rb + c * 256);

    const int xx = pix & 255, yy = pix >> 8;
    float sacc = sa_b[0];
    const float* ab = amx + (size_t)b * 2 * PLANE;
#pragma unroll
    for (int cc = 0; cc < 2; cc++)
#pragma unroll
        for (int dy2 = -1; dy2 <= 1; dy2++)
#pragma unroll
            for (int dx2 = -1; dx2 <= 1; dx2++) {
                int gx = xx + dx2; gx = gx < 0 ? 1 : (gx >= WW ? 2 * WW - 2 - gx : gx);
                int gy = yy + dy2; gy = gy < 0 ? 1 : (gy >= HH ? 2 * HH - 2 - gy : gy);
                sacc += sa_w[cc * 9 + (dy2 + 1) * 3 + (dx2 + 1)]
                      * ab[(size_t)cc * PLANE + gy * WW + gx];
            }
    const float sig = 1.f / (1.f + expf(-sacc));

    f32x16 accA = (f32x16)0.f, accB = (f32x16)0.f;
#pragma unroll
    for (int c = 0; c < 4; c++) {
        const s16x8 bh = fragpack(Bh[c]);
        const s16x8 ah = fragpack(KAh[c]), al = fragpack(KAl[c]);
        const s16x8 ch = fragpack(KBh[c]), cl = fragpack(KBl[c]);
        accA = __builtin_amdgcn_mfma_f32_32x32x16_bf16(ah, bh, accA, 0, 0, 0);
        accA = __builtin_amdgcn_mfma_f32_32x32x16_bf16(al, bh, accA, 0, 0, 0);
        accB = __builtin_amdgcn_mfma_f32_32x32x16_bf16(ch, bh, accB, 0, 0, 0);
        accB = __builtin_amdgcn_mfma_f32_32x32x16_bf16(cl, bh, accB, 0, 0, 0);
    }
#pragma unroll
    for (int j = 0; j < 16; j++) {
        const int row = (j & 3) + 8 * (j >> 2) + 4 * half;
        const int oc = mt * 32 + row;
        const size_t idx = ((size_t)b * 64 + oc) * PLANE + pix;
        out[idx] = x[idx] + hcb[oc] + sig * accA[j] + accB[j];
    }
}

extern "C" void kernel_launch(void* const* d_in, const int* in_sizes, int n_in,
                              void* d_out, int out_size, void* d_ws, size_t ws_size,
                              hipStream_t stream) {
    const float* x   = (const float*)d_in[0];
    const float* h   = (const float*)d_in[1];
    const float* c1w = (const float*)d_in[2];
    const float* c1b = (const float*)d_in[3];
    const float* pa  = (const float*)d_in[4];
    const float* c2w = (const float*)d_in[5];
    const float* c2b = (const float*)d_in[6];
    const float* saw = (const float*)d_in[7];
    const float* sab = (const float*)d_in[8];
    const float* cw1 = (const float*)d_in[9];
    const float* cb1 = (const float*)d_in[10];
    const float* caa = (const float*)d_in[11];
    const float* cw2 = (const float*)d_in[12];
    const float* cb2 = (const float*)d_in[13];
    const float* fcw = (const float*)d_in[14];
    const float* fcb = (const float*)d_in[15];
    const float* k1w = (const float*)d_in[16];
    const float* k1b = (const float*)d_in[17];
    const float* k2w = (const float*)d_in[18];
    const float* k2b = (const float*)d_in[19];
    const float* k3w = (const float*)d_in[20];
    const float* k3b = (const float*)d_in[21];
    const float* hcb = (const float*)d_in[22];
    float* out = (float*)d_out;

    char* ws = (char*)d_ws;
    const size_t SZ_Q = (size_t)8 * PLANE * 32 * 4;   // 67,108,864 (packed)
    uint*  r1p = (uint*)(ws + SZ_Q);                  // conv1 out (hi)
    uint*  rph = (uint*)(ws + 2 * SZ_Q);              // conv2 out hi
    float* amx   = (float*)ws;                        // region [0,SZ_Q) free
    uint*  kAhi  = (uint*)(ws + (size_t)8 * 3 * PLANE * 4 + 4096);
    uint*  kAlo  = kAhi + 8 * 2048;
    uint*  kBhi  = kAlo + 8 * 2048;
    uint*  kBlo  = kBhi + 8 * 2048;

    // weight packs + g live in d_out (dead until final_mfma overwrites it)
    uint* wsp = (uint*)d_out;
    uint* wh1 = wsp;          uint* wl1 = wsp + 18432;
    uint* wh2 = wsp + 36864;  uint* wl2 = wsp + 55296;
    float* g  = (float*)(wsp + 73728);                // 512 floats in d_out

    wprep_kernel<<<dim3(72, 2), 256, 0, stream>>>(c1w, c2w, wh1, wl1, wh2, wl2);
    hipMemsetAsync(g, 0, 512 * sizeof(float), stream);

    dim3 cgrid(WW / 32, HH / 4, 8);  // (8, 64, 8)
    conv_mfma<1><<<cgrid, 256, 0, stream>>>(x, nullptr, wh1, wl1, c1b, pa, r1p,
                                            nullptr, nullptr);
    conv_mfma<2><<<cgrid, 256, 0, stream>>>(nullptr, r1p, wh2, wl2, c2b, nullptr,
                                            rph, amx, g);

    mlp_kernel<<<dim3(8, 16), 256, 0, stream>>>(h, g, cw1, cb1, caa, cw2, cb2,
                                      fcw, fcb, k1w, k1b, k2w, k2b, k3w, k3b,
                                      kAhi, kAlo, kBhi, kBlo);
    final_mfma<<<dim3(PLANE / 64, 8), 256, 0, stream>>>(
        x, rph, amx, kAhi, kAlo, kBhi, kBlo, saw, sab, hcb, out);
}

// Round 23
// 506.750 us; speedup vs baseline: 2.5075x; 1.0165x over previous
//
#include <hip/hip_runtime.h>
#include <math.h>

#define HH 256
#define WW 256
#define CC 64
#define PLANE (HH*WW)

typedef short s16x8 __attribute__((ext_vector_type(8)));
typedef float f32x16 __attribute__((ext_vector_type(16)));
typedef unsigned int uint;
typedef uint u32x4v __attribute__((ext_vector_type(4)));

__device__ inline uint bf16rne(float f) {
    uint u = __float_as_uint(f);
    return (u + 0x7FFFu + ((u >> 16) & 1u)) >> 16;
}
__device__ inline float bf16val(uint h) { return __uint_as_float(h << 16); }
__device__ inline s16x8 fragpack(uint4 q) {
    u32x4v t = {q.x, q.y, q.z, q.w};
    return __builtin_bit_cast(s16x8, t);
}
// activation fragment-slot layout: dword (pix, dwi) at
//   (pix>>5)*1024 + (dwi>>2)*128 + (pix&31)*4 + (dwi&3)
__device__ inline size_t chunk_addr(int pix, int c2) {
    return (size_t)(pix >> 5) * 1024 + c2 * 128 + (pix & 31) * 4;
}
// weight fragment-slot layout: dword (tap, oc, dwi) at
//   tap*2048 + (dwi>>2)*256 + oc*4 + (dwi&3)   -> lane-dense dwordx4 loads

// ---------------- weight prep: split fp32 W into bf16 hi/lo + zero g --------
__global__ __launch_bounds__(256) void wprep_kernel(
    const float* __restrict__ w1, const float* __restrict__ w2,
    uint* __restrict__ wh1, uint* __restrict__ wl1,
    uint* __restrict__ wh2, uint* __restrict__ wl2,
    float* __restrict__ g)
{
    const int idx = blockIdx.x * 256 + threadIdx.x;      // 0..18431
    if (blockIdx.x == 0 && blockIdx.y == 0) {            // fold g memset
        g[threadIdx.x] = 0.f;
        g[threadIdx.x + 256] = 0.f;
    }
    const float* w = blockIdx.y ? w2 : w1;
    uint* wh = blockIdx.y ? wh2 : wh1;
    uint* wl = blockIdx.y ? wl2 : wl1;
    const int tap = idx >> 11;           // 9
    const int oc  = (idx >> 5) & 63;     // 64
    const int icp = idx & 31;            // 32 ic-pairs (dword index)
    float w0 = w[(oc * 64 + 2 * icp) * 9 + tap];
    float w1v = w[(oc * 64 + 2 * icp + 1) * 9 + tap];
    uint h0 = bf16rne(w0); float l0 = w0 - bf16val(h0);
    uint h1 = bf16rne(w1v); float l1 = w1v - bf16val(h1);
    const int a = tap * 2048 + (icp >> 2) * 256 + oc * 4 + (icp & 3);
    wh[a] = h0 | (h1 << 16);
    wl[a] = bf16rne(l0) | (bf16rne(l1) << 16);
}

// ---------------- conv 3x3 reflect via MFMA, 4-row tile, LDS halo ----------
// wave w: Mtile mt = w&1 (32 oc), row-pair rq = w>>1 (rows rq*2, rq*2+1).
// MODE 1: input = fp32 NCHW x (fused repack, swizzle on ds_write).
//         PReLU + fragment-slot (hi) out.
// MODE 2: input = fragment-slot packed r1p (dense staged). hi out +
//         fused chan mean/max + fused gpool partials.
// Per tap: {8 ds_read_b128 + NEXT tap's 8 weight dwordx4} -> sched_barrier(0)
// -> 16 MFMA.
// launch_bounds (256,3) is the ONLY stable point: allocator lands at 80 VGPR,
// zero spill. (256,4) -> 64 VGPR + 270MB scratch; (256,6) -> acc spills, 1.3GB.
#define HPIX 204                 // 6*34 halo pixels
template<int MODE>
__global__ __launch_bounds__(256, 3) void conv_mfma(
    const float* __restrict__ xf,   // MODE 1: fp32 NCHW input
    const uint* __restrict__ xin,   // MODE 2: fragment-slot packed input
    const uint* __restrict__ wh, const uint* __restrict__ wl,
    const float* __restrict__ bias, const float* __restrict__ prelu,
    uint* __restrict__ op, float* __restrict__ amx, float* __restrict__ gsum)
{
    __shared__ uint lds[HPIX * 32];          // 26,112 B
    const int tid  = threadIdx.x;
    const int lane = tid & 63;
    const int wid  = tid >> 6;
    const int x0 = blockIdx.x * 32;
    const int y0 = blockIdx.y * 4;
    const int b  = blockIdx.z;
    const int colx = lane & 31;
    const int half = lane >> 5;
    const int mt = wid & 1;          // Mtile (oc group of 32)
    const int rq = wid >> 1;         // row pair: rows rq*2, rq*2+1

    // ---- stage halo
    if constexpr (MODE == 1) {
        // fused repack from fp32 NCHW: middle 32 cols
        const float* xb = xf + (size_t)b * CC * PLANE;
        const int cp = tid >> 3;       // channel pair 0..31
        const int q  = tid & 7;        // pixel quad 0..7
#pragma unroll
        for (int r = 0; r < 6; r++) {
            int gy = y0 - 1 + r; gy = gy < 0 ? 1 : (gy > 255 ? 254 : gy);
            const float* p0 = xb + (size_t)(2 * cp) * PLANE + gy * 256 + x0 + q * 4;
            const float4 a = *(const float4*)p0;
            const float4 c = *(const float4*)(p0 + PLANE);
            uint dd[4];
            dd[0] = bf16rne(a.x) | (bf16rne(c.x) << 16);
            dd[1] = bf16rne(a.y) | (bf16rne(c.y) << 16);
            dd[2] = bf16rne(a.z) | (bf16rne(c.z) << 16);
            dd[3] = bf16rne(a.w) | (bf16rne(c.w) << 16);
#pragma unroll
            for (int i = 0; i < 4; i++) {
                const int lpix = r * 34 + 1 + q * 4 + i;
                const int slot = (cp >> 2) ^ (lpix & 7);
                lds[(lpix * 8 + slot) * 4 + (cp & 3)] = dd[i];
            }
        }
        // edges: 6 rows x 2 cols x 32 cps
        if (tid < 192) {
            const int r = tid >> 5, cpe = tid & 31;
            int gy = y0 - 1 + r; gy = gy < 0 ? 1 : (gy > 255 ? 254 : gy);
#pragma unroll
            for (int e = 0; e < 2; e++) {
                int gx = e ? x0 + 32 : x0 - 1;
                gx = gx < 0 ? 1 : (gx > 255 ? 254 : gx);
                const float v0 = xb[(size_t)(2 * cpe) * PLANE + gy * 256 + gx];
                const float v1 = xb[(size_t)(2 * cpe + 1) * PLANE + gy * 256 + gx];
                const int lpix = r * 34 + (e ? 33 : 0);
                const int slot = (cpe >> 2) ^ (lpix & 7);
                lds[(lpix * 8 + slot) * 4 + (cpe & 3)] =
                    bf16rne(v0) | (bf16rne(v1) << 16);
            }
        }
    } else {
        // dense staged from fragment-slot packed input
        const uint* gb = xin + (size_t)b * PLANE * 32;
        uint4 st[6];
#pragma unroll
        for (int r = 0; r < 6; r++) {
            int gy = y0 - 1 + r; gy = gy < 0 ? 1 : (gy > 255 ? 254 : gy);
            st[r] = *(const uint4*)(gb + (size_t)(gy * 8 + (x0 >> 5)) * 1024 + tid * 4);
        }
        const int hcol = (tid & 31) + 1;
        const int c2s  = tid >> 5;
#pragma unroll
        for (int r = 0; r < 6; r++) {
            const int lpix = r * 34 + hcol;
            const int lslot = c2s ^ (lpix & 7);
            *(uint4*)&lds[(lpix * 8 + lslot) * 4] = st[r];
        }
        if (tid < 96) {
            const int r  = tid >> 4;
            const int e  = (tid >> 3) & 1;
            const int sl = tid & 7;
            int gy = y0 - 1 + r; gy = gy < 0 ? 1 : (gy > 255 ? 254 : gy);
            int gx = e ? x0 + 32 : x0 - 1;
            gx = gx < 0 ? 1 : (gx > 255 ? 254 : gx);
            const uint4 v = *(const uint4*)(gb + chunk_addr(gy * 256 + gx, sl));
            const int lpix = r * 34 + (e ? 33 : 0);
            const int lslot = sl ^ (lpix & 7);
            *(uint4*)&lds[(lpix * 8 + lslot) * 4] = v;
        }
    }

    // lane-dense weight base for this wave's Mtile; preload tap 0
    const uint* wbh = wh + half * 256 + (mt * 32 + colx) * 4;
    const uint* wbl = wl + half * 256 + (mt * 32 + colx) * 4;
    uint4 Hc[4], Lc[4];
#pragma unroll
    for (int c = 0; c < 4; c++) {
        Hc[c] = *(const uint4*)(wbh + c * 512);
        Lc[c] = *(const uint4*)(wbl + c * 512);
    }
    __syncthreads();

    f32x16 acc0 = (f32x16)0.f, acc1 = (f32x16)0.f;   // rows rq*2, rq*2+1

#pragma unroll
    for (int tap = 0; tap < 9; tap++) {
        const int dy = tap / 3, dx = tap % 3;
        const int pixb = (rq * 2 + dy) * 34 + dx + colx;   // row rq*2

        uint4 Ba[4], Bb[4];
#pragma unroll
        for (int c = 0; c < 4; c++) {
            const int c2 = c * 2 + half;
            const int p0 = pixb, p1 = pixb + 34;
            Ba[c] = *(const uint4*)&lds[(p0 * 8 + (c2 ^ (p0 & 7))) * 4];
            Bb[c] = *(const uint4*)&lds[(p1 * 8 + (c2 ^ (p1 & 7))) * 4];
        }
        uint4 Hn[4], Ln[4];
        if (tap < 8) {
#pragma unroll
            for (int c = 0; c < 4; c++) {
                Hn[c] = *(const uint4*)(wbh + (tap + 1) * 2048 + c * 512);
                Ln[c] = *(const uint4*)(wbl + (tap + 1) * 2048 + c * 512);
            }
        }
        __builtin_amdgcn_sched_barrier(0);
#pragma unroll
        for (int c = 0; c < 4; c++) {
            const s16x8 b0 = fragpack(Ba[c]), b1 = fragpack(Bb[c]);
            const s16x8 ah = fragpack(Hc[c]), al = fragpack(Lc[c]);
            acc0 = __builtin_amdgcn_mfma_f32_32x32x16_bf16(ah, b0, acc0, 0, 0, 0);
            acc1 = __builtin_amdgcn_mfma_f32_32x32x16_bf16(ah, b1, acc1, 0, 0, 0);
            acc0 = __builtin_amdgcn_mfma_f32_32x32x16_bf16(al, b0, acc0, 0, 0, 0);
            acc1 = __builtin_amdgcn_mfma_f32_32x32x16_bf16(al, b1, acc1, 0, 0, 0);
        }
        if (tap < 8) {
#pragma unroll
            for (int c = 0; c < 4; c++) { Hc[c] = Hn[c]; Lc[c] = Ln[c]; }
        }
    }

    // ---- epilogue. C/D layout (32x32): col=lane&31 (pixel), row=(j&3)+8*(j>>2)+4*half (oc)
    const int pcol = colx, seg = half;
    const int pixg = (y0 + wid) * 256 + x0 + pcol;
    __syncthreads();                    // halo reads done; reuse lds for transpose
#define STH(ACC, RR, DOPRELU) { \
    _Pragma("unroll") \
    for (int j = 0; j < 16; j += 2) { \
        const int row = (j & 3) + 8 * (j >> 2) + 4 * half; \
        const int oc = mt * 32 + row; \
        float v0 = ACC[j]     + bias[oc]; \
        float v1 = ACC[j + 1] + bias[oc + 1]; \
        if (DOPRELU) { \
            const float a0 = prelu[oc], a1 = prelu[oc + 1]; \
            v0 = fmaxf(v0, 0.f) + a0 * fminf(v0, 0.f); \
            v1 = fmaxf(v1, 0.f) + a1 * fminf(v1, 0.f); \
        } \
        const int icp = oc >> 1; \
        lds[((RR) * 32 + icp) * 32 + (colx ^ icp)] = \
            bf16rne(v0) | (bf16rne(v1) << 16); \
    } }
    STH(acc0, rq * 2, (MODE == 1)) STH(acc1, rq * 2 + 1, (MODE == 1))
#undef STH
    __syncthreads();
    uint d[16];
#pragma unroll
    for (int i = 0; i < 16; i++) {
        const int icp = seg * 16 + i;
        d[i] = lds[(wid * 32 + icp) * 32 + (pcol ^ icp)];
    }
    uint* o = op + (size_t)b * PLANE * 32 + chunk_addr(pixg, seg * 4);
#pragma unroll
    for (int k = 0; k < 4; k++)
        *(uint4*)(o + k * 128) = make_uint4(d[4*k], d[4*k+1], d[4*k+2], d[4*k+3]);

    if constexpr (MODE == 2) {
        float s_ = 0.f, m_ = -INFINITY;
#pragma unroll
        for (int i = 0; i < 16; i++) {
            float ve = bf16val(d[i] & 0xffffu);
            float vo = bf16val(d[i] >> 16);
            s_ += ve + vo;
            m_ = fmaxf(m_, fmaxf(ve, vo));
        }
        const int cp_g = tid & 31;
        const int hr_g = tid >> 5;
        const int row_g = hr_g >> 1;
        const int pc0_g = (hr_g & 1) * 16;
        float gs0 = 0.f, gs1 = 0.f;
#pragma unroll
        for (int p = 0; p < 16; p++) {
            const int pc = pc0_g + p;
            const uint v = lds[(row_g * 32 + cp_g) * 32 + (pc ^ cp_g)];
            gs0 += bf16val(v & 0xffffu);
            gs1 += bf16val(v >> 16);
        }
        s_ += __shfl_xor(s_, 32, 64);
        m_ = fmaxf(m_, __shfl_xor(m_, 32, 64));
        if (seg == 0) {
            amx[(size_t)b * 2 * PLANE + pixg] = s_ * (1.f / 64.f);
            amx[(size_t)b * 2 * PLANE + PLANE + pixg] = m_;
        }
        __syncthreads();
        lds[4096 + hr_g * 64 + 2 * cp_g]     = __float_as_uint(gs0);
        lds[4096 + hr_g * 64 + 2 * cp_g + 1] = __float_as_uint(gs1);
        __syncthreads();
        if (tid < 64) {
            float t = 0.f;
#pragma unroll
            for (int h8 = 0; h8 < 8; h8++)
                t += __uint_as_float(lds[4096 + h8 * 64 + tid]);
            atomicAdd(&gsum[b * 64 + tid], t * (1.f / PLANE));
        }
    }
}

// ---------------- tiny MLPs -> hyper kernels, fragment-slot (hi only) ------
// grid (8, 16): every block redundantly computes the tiny chain, then handles
// a disjoint 256-output slice of k3. Kernel lo-residual dropped (below the
// r-side noise floor, cf. round-16 r-lo drop: absmax unchanged).
__global__ __launch_bounds__(256) void mlp_kernel(
    const float* __restrict__ h, const float* __restrict__ g,
    const float* __restrict__ ca_w1, const float* __restrict__ ca_b1,
    const float* __restrict__ ca_a,
    const float* __restrict__ ca_w2, const float* __restrict__ ca_b2,
    const float* __restrict__ fc_w, const float* __restrict__ fc_b,
    const float* __restrict__ k1_w, const float* __restrict__ k1_b,
    const float* __restrict__ k2_w, const float* __restrict__ k2_b,
    const float* __restrict__ k3_w, const float* __restrict__ k3_b,
    uint* __restrict__ kAhi, uint* __restrict__ kBhi)
{
    int b = blockIdx.x, tid = threadIdx.x;
    __shared__ float gb[64], t16[16], u32[32], v32[32], cg1[32], casig[64];

    if (tid < 64) gb[tid] = g[b * 64 + tid];
    __syncthreads();

    if (tid < 16) {
        float s = fc_b[tid];
        for (int j = 0; j < 16; j++) s += fc_w[tid * 16 + j] * h[b * 16 + j];
        t16[tid] = s >= 0.f ? s : 0.01f * s;
    }
    if (tid < 32) {
        float c1 = ca_b1[tid];
        for (int j = 0; j < 64; j++) c1 += ca_w1[tid * 64 + j] * gb[j];
        cg1[tid] = fmaxf(c1, 0.f) + ca_a[tid] * fminf(c1, 0.f);
    }
    __syncthreads();
    if (tid < 32) {
        float s = k1_b[tid];
        for (int j = 0; j < 16; j++) s += k1_w[tid * 16 + j] * t16[j];
        u32[tid] = s >= 0.f ? s : 0.01f * s;
    }
    if (tid < 64) {
        float c2 = ca_b2[tid];
        for (int j = 0; j < 32; j++) c2 += ca_w2[tid * 32 + j] * cg1[j];
        casig[tid] = 1.f / (1.f + expf(-c2));
    }
    __syncthreads();
    if (tid < 32) {
        float s = k2_b[tid];
        for (int j = 0; j < 32; j++) s += k2_w[tid * 32 + j] * u32[j];
        v32[tid] = s >= 0.f ? s : 0.01f * s;
    }
    __syncthreads();
    // k3: this block's 256-output slice; adjacent pairs -> one packed dword
    {
        const int o2 = blockIdx.y * 256 + tid;    // 0..4095
        const int o = o2 * 2;
        const int oc = o >> 7;        // /128
        const int i = o & 127;        // even
        float s0 = k3_b[o], s1 = k3_b[o + 1];
        for (int j = 0; j < 32; j++) {
            s0 += k3_w[(size_t)o * 32 + j] * v32[j];
            s1 += k3_w[(size_t)(o + 1) * 32 + j] * v32[j];
        }
        uint *hi;
        if (i < 64) { hi = kAhi; }
        else { s0 *= casig[i - 64]; s1 *= casig[i - 63]; hi = kBhi; }
        const int cp = (i & 63) >> 1;
        const size_t a = (size_t)b * 2048 + (cp >> 2) * 256 + oc * 4 + (cp & 3);
        hi[a] = bf16rne(s0) | (bf16rne(s1) << 16);
    }
}

// ---------------- final via MFMA + inlined spatial-attention conv -----------
// out = x + hcb + sig(sa3x3(amx))*(A.r) + (B.r);  r, A, B = bf16 hi only
__global__ __launch_bounds__(256, 8) void final_mfma(
    const float* __restrict__ x, const uint* __restrict__ rph,
    const float* __restrict__ amx,
    const uint* __restrict__ kAhi, const uint* __restrict__ kBhi,
    const float* __restrict__ sa_w, const float* __restrict__ sa_b,
    const float* __restrict__ hcb, float* __restrict__ out)
{
    const int tid = threadIdx.x;
    const int lane = tid & 63;
    const int wid = tid >> 6;
    const int mt = wid & 1;          // oc Mtile
    const int gq = wid >> 1;         // pixel group
    const int b = blockIdx.y;
    const int colx = lane & 31;
    const int half = lane >> 5;
    const int pix = blockIdx.x * 64 + gq * 32 + colx;
    const int pgroup = blockIdx.x * 2 + gq;   // pix >> 5

    const size_t kb = (size_t)b * 2048 + half * 256 + (size_t)(mt * 32 + colx) * 4;
    uint4 KAh[4], KBh[4];
#pragma unroll
    for (int c = 0; c < 4; c++) {
        KAh[c] = *(const uint4*)(kAhi + kb + c * 512);
        KBh[c] = *(const uint4*)(kBhi + kb + c * 512);
    }
    const size_t rb = (size_t)b * PLANE * 32 + (size_t)pgroup * 1024
                    + half * 128 + colx * 4;
    uint4 Bh[4];
#pragma unroll
    for (int c = 0; c < 4; c++)
        Bh[c] = *(const uint4*)(rph + rb + c * 256);

    const int xx = pix & 255, yy = pix >> 8;
    float sacc = sa_b[0];
    const float* ab = amx + (size_t)b * 2 * PLANE;
#pragma unroll
    for (int cc = 0; cc < 2; cc++)
#pragma unroll
        for (int dy2 = -1; dy2 <= 1; dy2++)
#pragma unroll
            for (int dx2 = -1; dx2 <= 1; dx2++) {
                int gx = xx + dx2; gx = gx < 0 ? 1 : (gx >= WW ? 2 * WW - 2 - gx : gx);
                int gy = yy + dy2; gy = gy < 0 ? 1 : (gy >= HH ? 2 * HH - 2 - gy : gy);
                sacc += sa_w[cc * 9 + (dy2 + 1) * 3 + (dx2 + 1)]
                      * ab[(size_t)cc * PLANE + gy * WW + gx];
            }
    const float sig = 1.f / (1.f + expf(-sacc));

    f32x16 accA = (f32x16)0.f, accB = (f32x16)0.f;
#pragma unroll
    for (int c = 0; c < 4; c++) {
        const s16x8 bh = fragpack(Bh[c]);
        accA = __builtin_amdgcn_mfma_f32_32x32x16_bf16(fragpack(KAh[c]), bh, accA, 0, 0, 0);
        accB = __builtin_amdgcn_mfma_f32_32x32x16_bf16(fragpack(KBh[c]), bh, accB, 0, 0, 0);
    }
#pragma unroll
    for (int j = 0; j < 16; j++) {
        const int row = (j & 3) + 8 * (j >> 2) + 4 * half;
        const int oc = mt * 32 + row;
        const size_t idx = ((size_t)b * 64 + oc) * PLANE + pix;
        out[idx] = x[idx] + hcb[oc] + sig * accA[j] + accB[j];
    }
}

extern "C" void kernel_launch(void* const* d_in, const int* in_sizes, int n_in,
                              void* d_out, int out_size, void* d_ws, size_t ws_size,
                              hipStream_t stream) {
    const float* x   = (const float*)d_in[0];
    const float* h   = (const float*)d_in[1];
    const float* c1w = (const float*)d_in[2];
    const float* c1b = (const float*)d_in[3];
    const float* pa  = (const float*)d_in[4];
    const float* c2w = (const float*)d_in[5];
    const float* c2b = (const float*)d_in[6];
    const float* saw = (const float*)d_in[7];
    const float* sab = (const float*)d_in[8];
    const float* cw1 = (const float*)d_in[9];
    const float* cb1 = (const float*)d_in[10];
    const float* caa = (const float*)d_in[11];
    const float* cw2 = (const float*)d_in[12];
    const float* cb2 = (const float*)d_in[13];
    const float* fcw = (const float*)d_in[14];
    const float* fcb = (const float*)d_in[15];
    const float* k1w = (const float*)d_in[16];
    const float* k1b = (const float*)d_in[17];
    const float* k2w = (const float*)d_in[18];
    const float* k2b = (const float*)d_in[19];
    const float* k3w = (const float*)d_in[20];
    const float* k3b = (const float*)d_in[21];
    const float* hcb = (const float*)d_in[22];
    float* out = (float*)d_out;

    char* ws = (char*)d_ws;
    const size_t SZ_Q = (size_t)8 * PLANE * 32 * 4;   // 67,108,864 (packed)
    uint*  r1p = (uint*)(ws + SZ_Q);                  // conv1 out (hi)
    uint*  rph = (uint*)(ws + 2 * SZ_Q);              // conv2 out hi
    float* amx   = (float*)ws;                        // region [0,SZ_Q) free
    uint*  kAhi  = (uint*)(ws + (size_t)8 * 3 * PLANE * 4 + 4096);
    uint*  kBhi  = kAhi + 8 * 2048;

    // weight packs + g live in d_out (dead until final_mfma overwrites it)
    uint* wsp = (uint*)d_out;
    uint* wh1 = wsp;          uint* wl1 = wsp + 18432;
    uint* wh2 = wsp + 36864;  uint* wl2 = wsp + 55296;
    float* g  = (float*)(wsp + 73728);                // 512 floats in d_out

    wprep_kernel<<<dim3(72, 2), 256, 0, stream>>>(c1w, c2w, wh1, wl1, wh2, wl2, g);

    dim3 cgrid(WW / 32, HH / 4, 8);  // (8, 64, 8)
    conv_mfma<1><<<cgrid, 256, 0, stream>>>(x, nullptr, wh1, wl1, c1b, pa, r1p,
                                            nullptr, nullptr);
    conv_mfma<2><<<cgrid, 256, 0, stream>>>(nullptr, r1p, wh2, wl2, c2b, nullptr,
                                            rph, amx, g);

    mlp_kernel<<<dim3(8, 16), 256, 0, stream>>>(h, g, cw1, cb1, caa, cw2, cb2,
                                      fcw, fcb, k1w, k1b, k2w, k2b, k3w, k3b,
                                      kAhi, kBhi);
    final_mfma<<<dim3(PLANE / 64, 8), 256, 0, stream>>>(
        x, rph, amx, kAhi, kBhi, saw, sab, hcb, out);
}

// Round 24
// 485.074 us; speedup vs baseline: 2.6196x; 1.0447x over previous
//
#include <hip/hip_runtime.h>
#include <math.h>

#define HH 256
#define WW 256
#define CC 64
#define PLANE (HH*WW)

typedef short s16x8 __attribute__((ext_vector_type(8)));
typedef float f32x16 __attribute__((ext_vector_type(16)));
typedef unsigned int uint;
typedef uint u32x4v __attribute__((ext_vector_type(4)));

__device__ inline uint bf16rne(float f) {
    uint u = __float_as_uint(f);
    return (u + 0x7FFFu + ((u >> 16) & 1u)) >> 16;
}
__device__ inline float bf16val(uint h) { return __uint_as_float(h << 16); }
__device__ inline s16x8 fragpack(uint4 q) {
    u32x4v t = {q.x, q.y, q.z, q.w};
    return __builtin_bit_cast(s16x8, t);
}
// activation fragment-slot layout: dword (pix, dwi) at
//   (pix>>5)*1024 + (dwi>>2)*128 + (pix&31)*4 + (dwi&3)
__device__ inline size_t chunk_addr(int pix, int c2) {
    return (size_t)(pix >> 5) * 1024 + c2 * 128 + (pix & 31) * 4;
}
// weight fragment-slot layout: dword (tap, oc, dwi) at
//   tap*2048 + (dwi>>2)*256 + oc*4 + (dwi&3)   -> lane-dense dwordx4 loads

// ---------------- weight prep: split fp32 W into bf16 hi/lo + zero g --------
__global__ __launch_bounds__(256) void wprep_kernel(
    const float* __restrict__ w1, const float* __restrict__ w2,
    uint* __restrict__ wh1, uint* __restrict__ wl1,
    uint* __restrict__ wh2, uint* __restrict__ wl2,
    float* __restrict__ g)
{
    const int idx = blockIdx.x * 256 + threadIdx.x;      // 0..18431
    if (blockIdx.x == 0 && blockIdx.y == 0) {            // fold g memset
        g[threadIdx.x] = 0.f;
        g[threadIdx.x + 256] = 0.f;
    }
    const float* w = blockIdx.y ? w2 : w1;
    uint* wh = blockIdx.y ? wh2 : wh1;
    uint* wl = blockIdx.y ? wl2 : wl1;
    const int tap = idx >> 11;           // 9
    const int oc  = (idx >> 5) & 63;     // 64
    const int icp = idx & 31;            // 32 ic-pairs (dword index)
    float w0 = w[(oc * 64 + 2 * icp) * 9 + tap];
    float w1v = w[(oc * 64 + 2 * icp + 1) * 9 + tap];
    uint h0 = bf16rne(w0); float l0 = w0 - bf16val(h0);
    uint h1 = bf16rne(w1v); float l1 = w1v - bf16val(h1);
    const int a = tap * 2048 + (icp >> 2) * 256 + oc * 4 + (icp & 3);
    wh[a] = h0 | (h1 << 16);
    wl[a] = bf16rne(l0) | (bf16rne(l1) << 16);
}

// ---------------- conv 3x3 reflect via MFMA, 4-row tile, LDS halo ----------
// wave w: Mtile mt = w&1 (32 oc), row-pair rq = w>>1 (rows rq*2, rq*2+1).
// XCD swizzle (T1): bijective swz = (wgid&7)*512 + wgid/8 gives each XCD one
// contiguous batch -> y-adjacent tiles (sharing halo rows) land on the same
// per-XCD L2 -> halo re-reads become L2 hits instead of HBM/L3 fetches.
// MODE 1: input = fp32 NCHW x (fused repack, swizzle on ds_write).
//         PReLU + fragment-slot (hi) out.
// MODE 2: input = fragment-slot packed r1p (dense staged). hi out +
//         fused chan mean/max + fused gpool partials.
// Per tap: {8 ds_read_b128 + NEXT tap's 8 weight dwordx4} -> sched_barrier(0)
// -> 16 MFMA.
// launch_bounds (256,3) is the ONLY stable point: allocator lands at 80 VGPR,
// zero spill. (256,4) -> 64 VGPR + 270MB scratch; (256,6) -> acc spills, 1.3GB.
#define HPIX 204                 // 6*34 halo pixels
template<int MODE>
__global__ __launch_bounds__(256, 3) void conv_mfma(
    const float* __restrict__ xf,   // MODE 1: fp32 NCHW input
    const uint* __restrict__ xin,   // MODE 2: fragment-slot packed input
    const uint* __restrict__ wh, const uint* __restrict__ wl,
    const float* __restrict__ bias, const float* __restrict__ prelu,
    uint* __restrict__ op, float* __restrict__ amx, float* __restrict__ gsum)
{
    __shared__ uint lds[HPIX * 32];          // 26,112 B
    const int tid  = threadIdx.x;
    const int lane = tid & 63;
    const int wid  = tid >> 6;
    // XCD-aware bijective swizzle of the 4096-block grid (8,64,8)
    const int wgid = blockIdx.x + (blockIdx.y << 3) + (blockIdx.z << 9);
    const int swz  = ((wgid & 7) << 9) + (wgid >> 3);
    const int x0 = (swz & 7) * 32;
    const int y0 = ((swz >> 3) & 63) * 4;
    const int b  = swz >> 9;
    const int colx = lane & 31;
    const int half = lane >> 5;
    const int mt = wid & 1;          // Mtile (oc group of 32)
    const int rq = wid >> 1;         // row pair: rows rq*2, rq*2+1

    // ---- stage halo
    if constexpr (MODE == 1) {
        // fused repack from fp32 NCHW: middle 32 cols
        const float* xb = xf + (size_t)b * CC * PLANE;
        const int cp = tid >> 3;       // channel pair 0..31
        const int q  = tid & 7;        // pixel quad 0..7
#pragma unroll
        for (int r = 0; r < 6; r++) {
            int gy = y0 - 1 + r; gy = gy < 0 ? 1 : (gy > 255 ? 254 : gy);
            const float* p0 = xb + (size_t)(2 * cp) * PLANE + gy * 256 + x0 + q * 4;
            const float4 a = *(const float4*)p0;
            const float4 c = *(const float4*)(p0 + PLANE);
            uint dd[4];
            dd[0] = bf16rne(a.x) | (bf16rne(c.x) << 16);
            dd[1] = bf16rne(a.y) | (bf16rne(c.y) << 16);
            dd[2] = bf16rne(a.z) | (bf16rne(c.z) << 16);
            dd[3] = bf16rne(a.w) | (bf16rne(c.w) << 16);
#pragma unroll
            for (int i = 0; i < 4; i++) {
                const int lpix = r * 34 + 1 + q * 4 + i;
                const int slot = (cp >> 2) ^ (lpix & 7);
                lds[(lpix * 8 + slot) * 4 + (cp & 3)] = dd[i];
            }
        }
        // edges: 6 rows x 2 cols x 32 cps
        if (tid < 192) {
            const int r = tid >> 5, cpe = tid & 31;
            int gy = y0 - 1 + r; gy = gy < 0 ? 1 : (gy > 255 ? 254 : gy);
#pragma unroll
            for (int e = 0; e < 2; e++) {
                int gx = e ? x0 + 32 : x0 - 1;
                gx = gx < 0 ? 1 : (gx > 255 ? 254 : gx);
                const float v0 = xb[(size_t)(2 * cpe) * PLANE + gy * 256 + gx];
                const float v1 = xb[(size_t)(2 * cpe + 1) * PLANE + gy * 256 + gx];
                const int lpix = r * 34 + (e ? 33 : 0);
                const int slot = (cpe >> 2) ^ (lpix & 7);
                lds[(lpix * 8 + slot) * 4 + (cpe & 3)] =
                    bf16rne(v0) | (bf16rne(v1) << 16);
            }
        }
    } else {
        // dense staged from fragment-slot packed input
        const uint* gb = xin + (size_t)b * PLANE * 32;
        uint4 st[6];
#pragma unroll
        for (int r = 0; r < 6; r++) {
            int gy = y0 - 1 + r; gy = gy < 0 ? 1 : (gy > 255 ? 254 : gy);
            st[r] = *(const uint4*)(gb + (size_t)(gy * 8 + (x0 >> 5)) * 1024 + tid * 4);
        }
        const int hcol = (tid & 31) + 1;
        const int c2s  = tid >> 5;
#pragma unroll
        for (int r = 0; r < 6; r++) {
            const int lpix = r * 34 + hcol;
            const int lslot = c2s ^ (lpix & 7);
            *(uint4*)&lds[(lpix * 8 + lslot) * 4] = st[r];
        }
        if (tid < 96) {
            const int r  = tid >> 4;
            const int e  = (tid >> 3) & 1;
            const int sl = tid & 7;
            int gy = y0 - 1 + r; gy = gy < 0 ? 1 : (gy > 255 ? 254 : gy);
            int gx = e ? x0 + 32 : x0 - 1;
            gx = gx < 0 ? 1 : (gx > 255 ? 254 : gx);
            const uint4 v = *(const uint4*)(gb + chunk_addr(gy * 256 + gx, sl));
            const int lpix = r * 34 + (e ? 33 : 0);
            const int lslot = sl ^ (lpix & 7);
            *(uint4*)&lds[(lpix * 8 + lslot) * 4] = v;
        }
    }

    // lane-dense weight base for this wave's Mtile; preload tap 0
    const uint* wbh = wh + half * 256 + (mt * 32 + colx) * 4;
    const uint* wbl = wl + half * 256 + (mt * 32 + colx) * 4;
    uint4 Hc[4], Lc[4];
#pragma unroll
    for (int c = 0; c < 4; c++) {
        Hc[c] = *(const uint4*)(wbh + c * 512);
        Lc[c] = *(const uint4*)(wbl + c * 512);
    }
    __syncthreads();

    f32x16 acc0 = (f32x16)0.f, acc1 = (f32x16)0.f;   // rows rq*2, rq*2+1

#pragma unroll
    for (int tap = 0; tap < 9; tap++) {
        const int dy = tap / 3, dx = tap % 3;
        const int pixb = (rq * 2 + dy) * 34 + dx + colx;   // row rq*2

        uint4 Ba[4], Bb[4];
#pragma unroll
        for (int c = 0; c < 4; c++) {
            const int c2 = c * 2 + half;
            const int p0 = pixb, p1 = pixb + 34;
            Ba[c] = *(const uint4*)&lds[(p0 * 8 + (c2 ^ (p0 & 7))) * 4];
            Bb[c] = *(const uint4*)&lds[(p1 * 8 + (c2 ^ (p1 & 7))) * 4];
        }
        uint4 Hn[4], Ln[4];
        if (tap < 8) {
#pragma unroll
            for (int c = 0; c < 4; c++) {
                Hn[c] = *(const uint4*)(wbh + (tap + 1) * 2048 + c * 512);
                Ln[c] = *(const uint4*)(wbl + (tap + 1) * 2048 + c * 512);
            }
        }
        __builtin_amdgcn_sched_barrier(0);
#pragma unroll
        for (int c = 0; c < 4; c++) {
            const s16x8 b0 = fragpack(Ba[c]), b1 = fragpack(Bb[c]);
            const s16x8 ah = fragpack(Hc[c]), al = fragpack(Lc[c]);
            acc0 = __builtin_amdgcn_mfma_f32_32x32x16_bf16(ah, b0, acc0, 0, 0, 0);
            acc1 = __builtin_amdgcn_mfma_f32_32x32x16_bf16(ah, b1, acc1, 0, 0, 0);
            acc0 = __builtin_amdgcn_mfma_f32_32x32x16_bf16(al, b0, acc0, 0, 0, 0);
            acc1 = __builtin_amdgcn_mfma_f32_32x32x16_bf16(al, b1, acc1, 0, 0, 0);
        }
        if (tap < 8) {
#pragma unroll
            for (int c = 0; c < 4; c++) { Hc[c] = Hn[c]; Lc[c] = Ln[c]; }
        }
    }

    // ---- epilogue. C/D layout (32x32): col=lane&31 (pixel), row=(j&3)+8*(j>>2)+4*half (oc)
    const int pcol = colx, seg = half;
    const int pixg = (y0 + wid) * 256 + x0 + pcol;
    __syncthreads();                    // halo reads done; reuse lds for transpose
#define STH(ACC, RR, DOPRELU) { \
    _Pragma("unroll") \
    for (int j = 0; j < 16; j += 2) { \
        const int row = (j & 3) + 8 * (j >> 2) + 4 * half; \
        const int oc = mt * 32 + row; \
        float v0 = ACC[j]     + bias[oc]; \
        float v1 = ACC[j + 1] + bias[oc + 1]; \
        if (DOPRELU) { \
            const float a0 = prelu[oc], a1 = prelu[oc + 1]; \
            v0 = fmaxf(v0, 0.f) + a0 * fminf(v0, 0.f); \
            v1 = fmaxf(v1, 0.f) + a1 * fminf(v1, 0.f); \
        } \
        const int icp = oc >> 1; \
        lds[((RR) * 32 + icp) * 32 + (colx ^ icp)] = \
            bf16rne(v0) | (bf16rne(v1) << 16); \
    } }
    STH(acc0, rq * 2, (MODE == 1)) STH(acc1, rq * 2 + 1, (MODE == 1))
#undef STH
    __syncthreads();
    uint d[16];
#pragma unroll
    for (int i = 0; i < 16; i++) {
        const int icp = seg * 16 + i;
        d[i] = lds[(wid * 32 + icp) * 32 + (pcol ^ icp)];
    }
    uint* o = op + (size_t)b * PLANE * 32 + chunk_addr(pixg, seg * 4);
#pragma unroll
    for (int k = 0; k < 4; k++)
        *(uint4*)(o + k * 128) = make_uint4(d[4*k], d[4*k+1], d[4*k+2], d[4*k+3]);

    if constexpr (MODE == 2) {
        float s_ = 0.f, m_ = -INFINITY;
#pragma unroll
        for (int i = 0; i < 16; i++) {
            float ve = bf16val(d[i] & 0xffffu);
            float vo = bf16val(d[i] >> 16);
            s_ += ve + vo;
            m_ = fmaxf(m_, fmaxf(ve, vo));
        }
        const int cp_g = tid & 31;
        const int hr_g = tid >> 5;
        const int row_g = hr_g >> 1;
        const int pc0_g = (hr_g & 1) * 16;
        float gs0 = 0.f, gs1 = 0.f;
#pragma unroll
        for (int p = 0; p < 16; p++) {
            const int pc = pc0_g + p;
            const uint v = lds[(row_g * 32 + cp_g) * 32 + (pc ^ cp_g)];
            gs0 += bf16val(v & 0xffffu);
            gs1 += bf16val(v >> 16);
        }
        s_ += __shfl_xor(s_, 32, 64);
        m_ = fmaxf(m_, __shfl_xor(m_, 32, 64));
        if (seg == 0) {
            amx[(size_t)b * 2 * PLANE + pixg] = s_ * (1.f / 64.f);
            amx[(size_t)b * 2 * PLANE + PLANE + pixg] = m_;
        }
        __syncthreads();
        lds[4096 + hr_g * 64 + 2 * cp_g]     = __float_as_uint(gs0);
        lds[4096 + hr_g * 64 + 2 * cp_g + 1] = __float_as_uint(gs1);
        __syncthreads();
        if (tid < 64) {
            float t = 0.f;
#pragma unroll
            for (int h8 = 0; h8 < 8; h8++)
                t += __uint_as_float(lds[4096 + h8 * 64 + tid]);
            atomicAdd(&gsum[b * 64 + tid], t * (1.f / PLANE));
        }
    }
}

// ---------------- tiny MLPs -> hyper kernels, fragment-slot (hi only) ------
// grid (8, 16): every block redundantly computes the tiny chain, then handles
// a disjoint 256-output slice of k3.
__global__ __launch_bounds__(256) void mlp_kernel(
    const float* __restrict__ h, const float* __restrict__ g,
    const float* __restrict__ ca_w1, const float* __restrict__ ca_b1,
    const float* __restrict__ ca_a,
    const float* __restrict__ ca_w2, const float* __restrict__ ca_b2,
    const float* __restrict__ fc_w, const float* __restrict__ fc_b,
    const float* __restrict__ k1_w, const float* __restrict__ k1_b,
    const float* __restrict__ k2_w, const float* __restrict__ k2_b,
    const float* __restrict__ k3_w, const float* __restrict__ k3_b,
    uint* __restrict__ kAhi, uint* __restrict__ kBhi)
{
    int b = blockIdx.x, tid = threadIdx.x;
    __shared__ float gb[64], t16[16], u32[32], v32[32], cg1[32], casig[64];

    if (tid < 64) gb[tid] = g[b * 64 + tid];
    __syncthreads();

    if (tid < 16) {
        float s = fc_b[tid];
        for (int j = 0; j < 16; j++) s += fc_w[tid * 16 + j] * h[b * 16 + j];
        t16[tid] = s >= 0.f ? s : 0.01f * s;
    }
    if (tid < 32) {
        float c1 = ca_b1[tid];
        for (int j = 0; j < 64; j++) c1 += ca_w1[tid * 64 + j] * gb[j];
        cg1[tid] = fmaxf(c1, 0.f) + ca_a[tid] * fminf(c1, 0.f);
    }
    __syncthreads();
    if (tid < 32) {
        float s = k1_b[tid];
        for (int j = 0; j < 16; j++) s += k1_w[tid * 16 + j] * t16[j];
        u32[tid] = s >= 0.f ? s : 0.01f * s;
    }
    if (tid < 64) {
        float c2 = ca_b2[tid];
        for (int j = 0; j < 32; j++) c2 += ca_w2[tid * 32 + j] * cg1[j];
        casig[tid] = 1.f / (1.f + expf(-c2));
    }
    __syncthreads();
    if (tid < 32) {
        float s = k2_b[tid];
        for (int j = 0; j < 32; j++) s += k2_w[tid * 32 + j] * u32[j];
        v32[tid] = s >= 0.f ? s : 0.01f * s;
    }
    __syncthreads();
    // k3: this block's 256-output slice; adjacent pairs -> one packed dword
    {
        const int o2 = blockIdx.y * 256 + tid;    // 0..4095
        const int o = o2 * 2;
        const int oc = o >> 7;        // /128
        const int i = o & 127;        // even
        float s0 = k3_b[o], s1 = k3_b[o + 1];
        for (int j = 0; j < 32; j++) {
            s0 += k3_w[(size_t)o * 32 + j] * v32[j];
            s1 += k3_w[(size_t)(o + 1) * 32 + j] * v32[j];
        }
        uint *hi;
        if (i < 64) { hi = kAhi; }
        else { s0 *= casig[i - 64]; s1 *= casig[i - 63]; hi = kBhi; }
        const int cp = (i & 63) >> 1;
        const size_t a = (size_t)b * 2048 + (cp >> 2) * 256 + oc * 4 + (cp & 3);
        hi[a] = bf16rne(s0) | (bf16rne(s1) << 16);
    }
}

// ---------------- final via MFMA + inlined spatial-attention conv -----------
// out = x + hcb + sig(sa3x3(amx))*(A.r) + (B.r);  r, A, B = bf16 hi only
__global__ __launch_bounds__(256, 8) void final_mfma(
    const float* __restrict__ x, const uint* __restrict__ rph,
    const float* __restrict__ amx,
    const uint* __restrict__ kAhi, const uint* __restrict__ kBhi,
    const float* __restrict__ sa_w, const float* __restrict__ sa_b,
    const float* __restrict__ hcb, float* __restrict__ out)
{
    const int tid = threadIdx.x;
    const int lane = tid & 63;
    const int wid = tid >> 6;
    const int mt = wid & 1;          // oc Mtile
    const int gq = wid >> 1;         // pixel group
    const int b = blockIdx.y;
    const int colx = lane & 31;
    const int half = lane >> 5;
    const int pix = blockIdx.x * 64 + gq * 32 + colx;
    const int pgroup = blockIdx.x * 2 + gq;   // pix >> 5

    const size_t kb = (size_t)b * 2048 + half * 256 + (size_t)(mt * 32 + colx) * 4;
    uint4 KAh[4], KBh[4];
#pragma unroll
    for (int c = 0; c < 4; c++) {
        KAh[c] = *(const uint4*)(kAhi + kb + c * 512);
        KBh[c] = *(const uint4*)(kBhi + kb + c * 512);
    }
    const size_t rb = (size_t)b * PLANE * 32 + (size_t)pgroup * 1024
                    + half * 128 + colx * 4;
    uint4 Bh[4];
#pragma unroll
    for (int c = 0; c < 4; c++)
        Bh[c] = *(const uint4*)(rph + rb + c * 256);

    const int xx = pix & 255, yy = pix >> 8;
    float sacc = sa_b[0];
    const float* ab = amx + (size_t)b * 2 * PLANE;
#pragma unroll
    for (int cc = 0; cc < 2; cc++)
#pragma unroll
        for (int dy2 = -1; dy2 <= 1; dy2++)
#pragma unroll
            for (int dx2 = -1; dx2 <= 1; dx2++) {
                int gx = xx + dx2; gx = gx < 0 ? 1 : (gx >= WW ? 2 * WW - 2 - gx : gx);
                int gy = yy + dy2; gy = gy < 0 ? 1 : (gy >= HH ? 2 * HH - 2 - gy : gy);
                sacc += sa_w[cc * 9 + (dy2 + 1) * 3 + (dx2 + 1)]
                      * ab[(size_t)cc * PLANE + gy * WW + gx];
            }
    const float sig = 1.f / (1.f + expf(-sacc));

    f32x16 accA = (f32x16)0.f, accB = (f32x16)0.f;
#pragma unroll
    for (int c = 0; c < 4; c++) {
        const s16x8 bh = fragpack(Bh[c]);
        accA = __builtin_amdgcn_mfma_f32_32x32x16_bf16(fragpack(KAh[c]), bh, accA, 0, 0, 0);
        accB = __builtin_amdgcn_mfma_f32_32x32x16_bf16(fragpack(KBh[c]), bh, accB, 0, 0, 0);
    }
#pragma unroll
    for (int j = 0; j < 16; j++) {
        const int row = (j & 3) + 8 * (j >> 2) + 4 * half;
        const int oc = mt * 32 + row;
        const size_t idx = ((size_t)b * 64 + oc) * PLANE + pix;
        out[idx] = x[idx] + hcb[oc] + sig * accA[j] + accB[j];
    }
}

extern "C" void kernel_launch(void* const* d_in, const int* in_sizes, int n_in,
                              void* d_out, int out_size, void* d_ws, size_t ws_size,
                              hipStream_t stream) {
    const float* x   = (const float*)d_in[0];
    const float* h   = (const float*)d_in[1];
    const float* c1w = (const float*)d_in[2];
    const float* c1b = (const float*)d_in[3];
    const float* pa  = (const float*)d_in[4];
    const float* c2w = (const float*)d_in[5];
    const float* c2b = (const float*)d_in[6];
    const float* saw = (const float*)d_in[7];
    const float* sab = (const float*)d_in[8];
    const float* cw1 = (const float*)d_in[9];
    const float* cb1 = (const float*)d_in[10];
    const float* caa = (const float*)d_in[11];
    const float* cw2 = (const float*)d_in[12];
    const float* cb2 = (const float*)d_in[13];
    const float* fcw = (const float*)d_in[14];
    const float* fcb = (const float*)d_in[15];
    const float* k1w = (const float*)d_in[16];
    const float* k1b = (const float*)d_in[17];
    const float* k2w = (const float*)d_in[18];
    const float* k2b = (const float*)d_in[19];
    const float* k3w = (const float*)d_in[20];
    const float* k3b = (const float*)d_in[21];
    const float* hcb = (const float*)d_in[22];
    float* out = (float*)d_out;

    char* ws = (char*)d_ws;
    const size_t SZ_Q = (size_t)8 * PLANE * 32 * 4;   // 67,108,864 (packed)
    uint*  r1p = (uint*)(ws + SZ_Q);                  // conv1 out (hi)
    uint*  rph = (uint*)(ws + 2 * SZ_Q);              // conv2 out hi
    float* amx   = (float*)ws;                        // region [0,SZ_Q) free
    uint*  kAhi  = (uint*)(ws + (size_t)8 * 3 * PLANE * 4 + 4096);
    uint*  kBhi  = kAhi + 8 * 2048;

    // weight packs + g live in d_out (dead until final_mfma overwrites it)
    uint* wsp = (uint*)d_out;
    uint* wh1 = wsp;          uint* wl1 = wsp + 18432;
    uint* wh2 = wsp + 36864;  uint* wl2 = wsp + 55296;
    float* g  = (float*)(wsp + 73728);                // 512 floats in d_out

    wprep_kernel<<<dim3(72, 2), 256, 0, stream>>>(c1w, c2w, wh1, wl1, wh2, wl2, g);

    dim3 cgrid(WW / 32, HH / 4, 8);  // (8, 64, 8)
    conv_mfma<1><<<cgrid, 256, 0, stream>>>(x, nullptr, wh1, wl1, c1b, pa, r1p,
                                            nullptr, nullptr);
    conv_mfma<2><<<cgrid, 256, 0, stream>>>(nullptr, r1p, wh2, wl2, c2b, nullptr,
                                            rph, amx, g);

    mlp_kernel<<<dim3(8, 16), 256, 0, stream>>>(h, g, cw1, cb1, caa, cw2, cb2,
                                      fcw, fcb, k1w, k1b, k2w, k2b, k3w, k3b,
                                      kAhi, kBhi);
    final_mfma<<<dim3(PLANE / 64, 8), 256, 0, stream>>>(
        x, rph, amx, kAhi, kBhi, saw, sab, hcb, out);
}